// Round 5
// baseline (1850.809 us; speedup 1.0000x reference)
//
#include <hip/hip_runtime.h>
#include <math.h>

#define TT 2048
#define EE 768
#define HNN 12
#define HSS 64
#define NLAYER 6
#define FFD 3072
#define QKVN 2304

constexpr float LN_EPS = 1e-5f;
constexpr float ATT_SCALE = 0.03608439182435161f; // 1/sqrt(768) (reference divides by sqrt(n_embed))
// log2-domain scale: exp(x*A) == exp2(x*A*log2e)
constexpr float ATT_SCALE_L2E = 0.03608439182435161f * 1.4426950408889634f;

typedef __attribute__((ext_vector_type(8))) short bf16x8;
typedef __attribute__((ext_vector_type(4))) float f32x4;

__device__ __forceinline__ ushort f2bf(float f) {
    union { float f; uint u; } c; c.f = f;
    const uint u = c.u;
    return (ushort)((u + 0x7fffu + ((u >> 16) & 1u)) >> 16);
}

__device__ __forceinline__ void gload16(const void* g, void* l) {
    __builtin_amdgcn_global_load_lds((const __attribute__((address_space(1))) void*)g,
                                     (__attribute__((address_space(3))) void*)l, 16, 0, 0);
}

// ---------------------------------------------------------------- copy ----
__global__ __launch_bounds__(256) void copy4_kernel(float4* __restrict__ dst,
                                                    const float4* __restrict__ src, int n4) {
    int i = blockIdx.x * 256 + threadIdx.x;
    if (i < n4) dst[i] = src[i];
}

// ----------------------------------------------------------- layernorm ----
__global__ __launch_bounds__(256) void ln_kernel(const float* __restrict__ in,
                                                 const float* __restrict__ g,
                                                 const float* __restrict__ b,
                                                 ushort* __restrict__ out) {
    __shared__ float red[8];
    const int t = blockIdx.x;
    const int tid = threadIdx.x;
    const float* row = in + (size_t)t * EE;
    float v0 = row[tid], v1 = row[tid + 256], v2 = row[tid + 512];
    float s = v0 + v1 + v2;
#pragma unroll
    for (int m = 1; m < 64; m <<= 1) s += __shfl_xor(s, m, 64);
    if ((tid & 63) == 0) red[tid >> 6] = s;
    __syncthreads();
    const float mean = (red[0] + red[1] + red[2] + red[3]) * (1.0f / EE);
    const float d0 = v0 - mean, d1 = v1 - mean, d2 = v2 - mean;
    float qq = d0 * d0 + d1 * d1 + d2 * d2;
#pragma unroll
    for (int m = 1; m < 64; m <<= 1) qq += __shfl_xor(qq, m, 64);
    __syncthreads();
    if ((tid & 63) == 0) red[tid >> 6] = qq;
    __syncthreads();
    const float var = (red[0] + red[1] + red[2] + red[3]) * (1.0f / EE);
    const float rstd = rsqrtf(var + LN_EPS);
    ushort* orow = out + (size_t)t * EE;
    orow[tid]       = f2bf(d0 * rstd * g[tid]       + b[tid]);
    orow[tid + 256] = f2bf(d1 * rstd * g[tid + 256] + b[tid + 256]);
    orow[tid + 512] = f2bf(d2 * rstd * g[tid + 512] + b[tid + 512]);
}

// --------------------------------------------------- weight pack (fp32->bf16^T)
__device__ __forceinline__ void transpose64(const float* __restrict__ src, int sld,
                                            ushort* __restrict__ dst, int dld,
                                            int k0, int n0, int tid) {
    __shared__ float t[64][68];
#pragma unroll
    for (int p = 0; p < 4; p++) {
        const int kr = p * 16 + (tid >> 4);
        *(float4*)&t[kr][(tid & 15) * 4] =
            *(const float4*)&src[(size_t)(k0 + kr) * sld + n0 + (tid & 15) * 4];
    }
    __syncthreads();
#pragma unroll
    for (int q = 0; q < 2; q++) {
        const int nl = q * 32 + (tid >> 3);
        const int kc = (tid & 7) * 8;
        ushort v[8];
#pragma unroll
        for (int j = 0; j < 8; j++) v[j] = f2bf(t[kc + j][nl]);
        uint4 o;
        o.x = (uint)v[0] | ((uint)v[1] << 16);
        o.y = (uint)v[2] | ((uint)v[3] << 16);
        o.z = (uint)v[4] | ((uint)v[5] << 16);
        o.w = (uint)v[6] | ((uint)v[7] << 16);
        *(uint4*)&dst[(size_t)(n0 + nl) * dld + k0 + kc] = o;
    }
}

__global__ __launch_bounds__(256) void pack_t_kernel(const float* __restrict__ src, int sld,
                                                     ushort* __restrict__ dst, int dld) {
    transpose64(src, sld, dst, dld, blockIdx.x * 64, blockIdx.y * 64, threadIdx.x);
}

__global__ __launch_bounds__(256) void pack_qkv_kernel(const float* __restrict__ wq,
                                                       const float* __restrict__ wk,
                                                       const float* __restrict__ wv,
                                                       ushort* __restrict__ dst) {
    const int z = blockIdx.z;
    const int which = z / HNN, hd = z % HNN;
    const float* src = (which == 0 ? wq : which == 1 ? wk : wv) + (size_t)hd * EE * HSS;
    ushort* d = dst + (size_t)(which * EE + hd * HSS) * EE;
    transpose64(src, HSS, d, EE, blockIdx.x * 64, 0, threadIdx.x);
}

// ------------------------------------------------------------ V transpose ----
__global__ __launch_bounds__(256) void vtrans_kernel(const ushort* __restrict__ qkv,
                                                     ushort* __restrict__ vT) {
    const int t = blockIdx.x * 256 + threadIdx.x;  // 0..196607
    const int d = t & 63;
    const int rest = t >> 6;
    const int tb = rest & 255;   // token block of 8
    const int hd = rest >> 8;    // 0..11
    const ushort* src = qkv + 1536 + hd * 64 + d;
    ushort v[8];
#pragma unroll
    for (int j = 0; j < 8; j++) v[j] = src[(size_t)(tb * 8 + j) * QKVN];
    uint4 o;
    o.x = (uint)v[0] | ((uint)v[1] << 16);
    o.y = (uint)v[2] | ((uint)v[3] << 16);
    o.z = (uint)v[4] | ((uint)v[5] << 16);
    o.w = (uint)v[6] | ((uint)v[7] << 16);
    *(uint4*)&vT[((size_t)hd * 64 + d) * TT + tb * 8] = o;
}

// ---------------------------------------------------------- bf16 GEMM ----
// (unchanged from R6: XCD-contiguous remap, 2-phase pipeline, split-K EPI=1)
template <int EPI>
__global__ __launch_bounds__(256) void gemm_bf16(const ushort* __restrict__ A,
                                                 const ushort* __restrict__ Bt,
                                                 const float* __restrict__ b0,
                                                 const float* __restrict__ b1,
                                                 const float* __restrict__ b2,
                                                 float* __restrict__ outF,
                                                 ushort* __restrict__ outB,
                                                 int N, int K,
                                                 int nby, int KS, int Kslice) {
    __shared__ ushort Al[2][128 * 32];
    __shared__ ushort Bl[2][128 * 32];
    const int tid = threadIdx.x;
    const int wave = tid >> 6, lane = tid & 63;
    const int wm = wave >> 1, wn = wave & 1;
    const int l15 = lane & 15, q4 = lane >> 4;

    const int nwg = gridDim.x;
    const int wgid = ((int)blockIdx.x & 7) * (nwg >> 3) + ((int)blockIdx.x >> 3);
    const int mb = wgid % nby;
    const int t2 = wgid / nby;
    const int ks = t2 % KS;
    const int nb = t2 / KS;
    const int m0 = mb * 128, n0 = nb * 128;
    const int kbase = ks * Kslice;

    const int srow = lane >> 2;
    const int scb = (lane & 3) ^ ((lane >> 3) & 3);
    const ushort* Ag0 = A + (size_t)(m0 + wave * 16 + srow) * K + kbase + scb * 8;
    const ushort* Ag1 = Ag0 + (size_t)64 * K;
    const ushort* Bg0 = Bt + (size_t)(n0 + wave * 16 + srow) * K + kbase + scb * 8;
    const ushort* Bg1 = Bg0 + (size_t)64 * K;

    auto stage = [&](int buf, int kk) {
        const int off = kk * 32;
        gload16(Ag0 + off, &Al[buf][(wave * 16) * 32]);
        gload16(Ag1 + off, &Al[buf][(64 + wave * 16) * 32]);
        gload16(Bg0 + off, &Bl[buf][(wave * 16) * 32]);
        gload16(Bg1 + off, &Bl[buf][(64 + wave * 16) * 32]);
    };

    f32x4 acc[4][4];
#pragma unroll
    for (int i = 0; i < 4; i++)
#pragma unroll
        for (int j = 0; j < 4; j++) acc[i][j] = (f32x4){0.f, 0.f, 0.f, 0.f};

    stage(0, 0);
    __syncthreads();

    const int niter = Kslice >> 5;
    const int cq = (q4 ^ ((l15 >> 1) & 3)) * 8;

    for (int i = 0; i < niter; i++) {
        const int buf = i & 1;
        if (i + 1 < niter) stage(buf ^ 1, i + 1);
        bf16x8 af[4], bfr[4];
#pragma unroll
        for (int ii = 0; ii < 4; ii++)
            af[ii] = *(const bf16x8*)&Al[buf][(wm * 64 + ii * 16 + l15) * 32 + cq];
#pragma unroll
        for (int j = 0; j < 4; j++)
            bfr[j] = *(const bf16x8*)&Bl[buf][(wn * 64 + j * 16 + l15) * 32 + cq];
#pragma unroll
        for (int ii = 0; ii < 4; ii++)
#pragma unroll
            for (int j = 0; j < 4; j++)
                acc[ii][j] = __builtin_amdgcn_mfma_f32_16x16x32_bf16(af[ii], bfr[j], acc[ii][j], 0, 0, 0);
        __syncthreads();
    }

#pragma unroll
    for (int i = 0; i < 4; i++) {
        const int row = m0 + wm * 64 + i * 16 + q4 * 4;
#pragma unroll
        for (int j = 0; j < 4; j++) {
            const int col = n0 + wn * 64 + j * 16 + l15;
            float bias;
            if constexpr (EPI == 0)
                bias = (col < 768) ? b0[col] : (col < 1536 ? b1[col - 768] : b2[col - 1536]);
            else
                bias = (EPI == 1 && ks != 0) ? 0.f : b0[col];
#pragma unroll
            for (int r = 0; r < 4; r++) {
                const float v = acc[i][j][r] + bias;
                const size_t idx = (size_t)(row + r) * N + col;
                if constexpr (EPI == 0) {
                    outB[idx] = f2bf(v);
                } else if constexpr (EPI == 1) {
                    atomicAdd(&outF[idx], v);
                } else if constexpr (EPI == 2) {
                    outB[idx] = f2bf(0.5f * v * (1.0f + erff(v * 0.70710678118654752f)));
                } else {
                    outF[idx] = v;
                }
            }
        }
    }
}

// ----------------------------------------------------- MFMA attention ----
// R8: uniform-chunk per-wave flash attention with partial combine.
//  Chunk = (head, 16-row q-tile qi, key-slice c of 12 k-tiles=768 keys).
//  Per head: qi<48 -> 1 chunk (direct output), qi 48..95 -> 2, qi 96..127 -> 3.
//  240 chunks/head * 12 = 2880 waves (720 blocks): uniform size (<=12 iters)
//  -> no straggler blocks, ~2.8 waves/SIMD (was 1.5 with 3:1 imbalance).
//  Multi-chunk tiles write fp32 partials (O[16][64], m[16], l[16]) into the
//  idle ffb buffer; attn_combine merges with exp2(m_c - M) flash weights.
//  Per-iter math unchanged from R7 (swapped QK^T, exp2 softmax, rotation-
//  swizzled Ps roundtrip, K reg-double-buffer, V stream from vT).
__global__ __launch_bounds__(256, 4) void attn_mfma(const ushort* __restrict__ qkv,
                                                    const ushort* __restrict__ vT,
                                                    ushort* __restrict__ o_bf,
                                                    float* __restrict__ pbuf) {
    __shared__ __align__(16) uint Ps[4][16 * 36];

    const int tid = threadIdx.x;
    const int wave = tid >> 6, lane = tid & 63;
    const int l15 = lane & 15, q4 = lane >> 4;

    // chunk decode
    const int chunk = (int)blockIdx.x * 4 + wave;
    const int head = chunk / 240;
    const int t = chunk - head * 240;
    int qi, c;
    if (t < 48) { qi = t; c = 0; }
    else if (t < 144) { const int u = t - 48; qi = 48 + (u >> 1); c = u & 1; }
    else { const int u = t - 144; const int q3 = u / 3; qi = 96 + q3; c = u - q3 * 3; }
    const int nkt = (qi >> 2) + 1;           // total k-tiles for this q-tile
    const int kt_begin = c * 12;
    const int kt_end = min(kt_begin + 12, nkt);
    const bool direct = (qi < 48);
    const int qrow_g = qi * 16 + l15;

    // Q fragments (B-operand of swapped QK^T)
    const ushort* qp = qkv + (size_t)qrow_g * QKVN + head * 64;
    const bf16x8 qa0 = *(const bf16x8*)&qp[q4 * 8];
    const bf16x8 qa1 = *(const bf16x8*)&qp[32 + q4 * 8];

    // per-lane K / V^T bases
    const ushort* kbase = qkv + 768 + head * 64 + (size_t)l15 * QKVN + q4 * 8;
    const ushort* vbase = vT + ((size_t)head * 64 + l15) * TT + q4 * 8;

    float m_i = -1e30f, l_i = 0.f;
    f32x4 oacc[4];
#pragma unroll
    for (int n = 0; n < 4; n++) oacc[n] = (f32x4){0.f, 0.f, 0.f, 0.f};

    bf16x8 kA[8], kB[8], vC[8];
    // prologue: K tile kt_begin
    {
        const ushort* kp = kbase + (size_t)kt_begin * 64 * QKVN;
#pragma unroll
        for (int n = 0; n < 4; n++)
#pragma unroll
            for (int kb = 0; kb < 2; kb++)
                kA[n * 2 + kb] = *(const bf16x8*)(kp + (size_t)(n * 16) * QKVN + kb * 32);
    }

    uint* psrow = &Ps[wave][l15 * 36];

    auto body = [&](bf16x8* kc, bf16x8* kn, int kt) {
        // V^T for current tile (latency covered by QK^T + softmax)
        const ushort* vp = vbase + kt * 64;
#pragma unroll
        for (int n = 0; n < 4; n++)
#pragma unroll
            for (int kb = 0; kb < 2; kb++)
                vC[n * 2 + kb] = *(const bf16x8*)(vp + (size_t)(n * 16) * TT + kb * 32);
        // prefetch K for next tile
        if (kt + 1 < kt_end) {
            const ushort* kp = kbase + (size_t)(kt + 1) * 64 * QKVN;
#pragma unroll
            for (int n = 0; n < 4; n++)
#pragma unroll
                for (int kb = 0; kb < 2; kb++)
                    kn[n * 2 + kb] = *(const bf16x8*)(kp + (size_t)(n * 16) * QKVN + kb * 32);
        }
        // S^T = K Q^T : lane -> q-row l15, keys n*16 + q4*4 + rr
        f32x4 s[4];
#pragma unroll
        for (int n = 0; n < 4; n++) {
            f32x4 a = (f32x4){0.f, 0.f, 0.f, 0.f};
            a = __builtin_amdgcn_mfma_f32_16x16x32_bf16(kc[n * 2], qa0, a, 0, 0, 0);
            a = __builtin_amdgcn_mfma_f32_16x16x32_bf16(kc[n * 2 + 1], qa1, a, 0, 0, 0);
            s[n] = a;
        }
        // scale into log2 domain + causal mask (only the global last tile)
        float pe[16];
        const bool diag = (kt == nkt - 1);
#pragma unroll
        for (int n = 0; n < 4; n++) {
            const int k0 = kt * 64 + n * 16 + q4 * 4;
#pragma unroll
            for (int rr = 0; rr < 4; rr++) {
                float xv = s[n][rr] * ATT_SCALE_L2E;
                if (diag && (k0 + rr) > qrow_g) xv = -1e30f;
                pe[n * 4 + rr] = xv;
            }
        }
        // row max: pairwise tree + 2 shfl
        float t8[8];
#pragma unroll
        for (int i = 0; i < 8; i++) t8[i] = fmaxf(pe[i], pe[i + 8]);
        float mx = fmaxf(fmaxf(fmaxf(t8[0], t8[4]), fmaxf(t8[1], t8[5])),
                         fmaxf(fmaxf(t8[2], t8[6]), fmaxf(t8[3], t8[7])));
        mx = fmaxf(mx, __shfl_xor(mx, 16, 64));
        mx = fmaxf(mx, __shfl_xor(mx, 32, 64));
        const float nm = fmaxf(m_i, mx);
        const float al = exp2f(m_i - nm);
#pragma unroll
        for (int i = 0; i < 16; i++) pe[i] = exp2f(pe[i] - nm);
        float s8[8];
#pragma unroll
        for (int i = 0; i < 8; i++) s8[i] = pe[i] + pe[i + 8];
        float rs = ((s8[0] + s8[4]) + (s8[1] + s8[5])) + ((s8[2] + s8[6]) + (s8[3] + s8[7]));
        rs += __shfl_xor(rs, 16, 64);
        rs += __shfl_xor(rs, 32, 64);
        l_i = l_i * al + rs;
        m_i = nm;
        // alpha for O-rows q4*4+rr
        float alr[4];
#pragma unroll
        for (int rr = 0; rr < 4; rr++) alr[rr] = __shfl(al, q4 * 4 + rr, 64);
#pragma unroll
        for (int n = 0; n < 4; n++) {
            oacc[n][0] *= alr[0];
            oacc[n][1] *= alr[1];
            oacc[n][2] *= alr[2];
            oacc[n][3] *= alr[3];
        }
        // P -> A-fragments via per-wave LDS, rotation-swizzled (bank-optimal)
#pragma unroll
        for (int n = 0; n < 4; n++) {
            uint2 d2;
            d2.x = (uint)f2bf(pe[n * 4 + 0]) | ((uint)f2bf(pe[n * 4 + 1]) << 16);
            d2.y = (uint)f2bf(pe[n * 4 + 2]) | ((uint)f2bf(pe[n * 4 + 3]) << 16);
            *(uint2*)&psrow[(8 * n + 2 * q4 + 4 * l15) & 31] = d2;
        }
        const bf16x8 pa0 = *(const bf16x8*)&psrow[(4 * q4 + 4 * l15) & 31];
        const bf16x8 pa1 = *(const bf16x8*)&psrow[(16 + 4 * q4 + 4 * l15) & 31];
        // O += P V
#pragma unroll
        for (int n = 0; n < 4; n++) {
            oacc[n] = __builtin_amdgcn_mfma_f32_16x16x32_bf16(pa0, vC[n * 2], oacc[n], 0, 0, 0);
            oacc[n] = __builtin_amdgcn_mfma_f32_16x16x32_bf16(pa1, vC[n * 2 + 1], oacc[n], 0, 0, 0);
        }
    };

    int kt = kt_begin;
    for (;;) {
        body(kA, kB, kt);
        if (++kt >= kt_end) break;
        body(kB, kA, kt);
        if (++kt >= kt_end) break;
    }

    if (direct) {
        float lrec[4];
#pragma unroll
        for (int rr = 0; rr < 4; rr++) lrec[rr] = 1.0f / __shfl(l_i, q4 * 4 + rr, 64);
#pragma unroll
        for (int n = 0; n < 4; n++)
#pragma unroll
            for (int rr = 0; rr < 4; rr++)
                o_bf[(size_t)(qi * 16 + q4 * 4 + rr) * EE + head * 64 + n * 16 + l15] =
                    f2bf(oacc[n][rr] * lrec[rr]);
    } else {
        // partial: O[16][64] fp32 + m[16] + l[16], slot stride 1056 floats
        float* pb = pbuf + (size_t)((head * 80 + (qi - 48)) * 3 + c) * 1056;
#pragma unroll
        for (int n = 0; n < 4; n++)
#pragma unroll
            for (int rr = 0; rr < 4; rr++)
                pb[(q4 * 4 + rr) * 64 + n * 16 + l15] = oacc[n][rr];
        if (q4 == 0) {
            pb[1024 + l15] = m_i;
            pb[1040 + l15] = l_i;
        }
    }
}

// ------------------------------------------------- attention combine ----
// one wave per (head, qi>=48): merge 2-3 partials with flash weights.
__global__ __launch_bounds__(256) void attn_combine(const float* __restrict__ pbuf,
                                                    ushort* __restrict__ o_bf) {
    const int wave = threadIdx.x >> 6, lane = threadIdx.x & 63;
    const int task = (int)blockIdx.x * 4 + wave;
    const int head = task / 80;
    const int u = task - head * 80;
    const int qi = 48 + u;
    const int nc = (qi < 96) ? 2 : 3;
    const float* pb = pbuf + (size_t)((head * 80 + u) * 3) * 1056;

    for (int r = 0; r < 16; r++) {
        float m0 = pb[1024 + r];
        float m1 = pb[1056 + 1024 + r];
        float m2 = (nc == 3) ? pb[2112 + 1024 + r] : -1e30f;
        const float M = fmaxf(fmaxf(m0, m1), m2);
        const float w0 = exp2f(m0 - M);
        const float w1 = exp2f(m1 - M);
        const float w2 = (nc == 3) ? exp2f(m2 - M) : 0.f;
        float L = w0 * pb[1040 + r] + w1 * pb[1056 + 1040 + r];
        float v = w0 * pb[r * 64 + lane] + w1 * pb[1056 + r * 64 + lane];
        if (nc == 3) {
            L += w2 * pb[2112 + 1040 + r];
            v += w2 * pb[2112 + r * 64 + lane];
        }
        o_bf[(size_t)(qi * 16 + r) * EE + head * 64 + lane] = f2bf(v / L);
    }
}

// ---------------------------------------------------------------- head ----
__global__ __launch_bounds__(256) void head_kernel(const float* __restrict__ x,
                                                   const float* __restrict__ hw,
                                                   const float* __restrict__ hb,
                                                   float* __restrict__ out) {
    __shared__ float red[8];
    const int t = blockIdx.x, tid = threadIdx.x;
    const float* row = x + (size_t)t * EE;
    float s = row[tid] * hw[tid] + row[tid + 256] * hw[tid + 256] + row[tid + 512] * hw[tid + 512];
#pragma unroll
    for (int m = 1; m < 64; m <<= 1) s += __shfl_xor(s, m, 64);
    if ((tid & 63) == 0) red[tid >> 6] = s;
    __syncthreads();
    if (tid == 0) out[t] = red[0] + red[1] + red[2] + red[3] + hb[0];
}

// -------------------------------------------------------------- launch ----
extern "C" void kernel_launch(void* const* d_in, const int* in_sizes, int n_in,
                              void* d_out, int out_size, void* d_ws, size_t ws_size,
                              hipStream_t stream) {
    const float* idx   = (const float*)d_in[0];
    const float* wq    = (const float*)d_in[2];
    const float* bq    = (const float*)d_in[3];
    const float* wk    = (const float*)d_in[4];
    const float* bk    = (const float*)d_in[5];
    const float* wv    = (const float*)d_in[6];
    const float* bv    = (const float*)d_in[7];
    const float* wproj = (const float*)d_in[8];
    const float* bproj = (const float*)d_in[9];
    const float* ln1g  = (const float*)d_in[10];
    const float* ln1b  = (const float*)d_in[11];
    const float* ln2g  = (const float*)d_in[12];
    const float* ln2b  = (const float*)d_in[13];
    const float* w1    = (const float*)d_in[14];
    const float* b1    = (const float*)d_in[15];
    const float* w2    = (const float*)d_in[16];
    const float* b2    = (const float*)d_in[17];
    const float* lnfg  = (const float*)d_in[18];
    const float* lnfb  = (const float*)d_in[19];
    const float* fw1   = (const float*)d_in[20];
    const float* fb1   = (const float*)d_in[21];
    const float* fw2   = (const float*)d_in[22];
    const float* fb2   = (const float*)d_in[23];
    const float* hw    = (const float*)d_in[24];
    const float* hb    = (const float*)d_in[25];
    float* out = (float*)d_out;

    // ---- workspace carve (~50 MB) ----
    char* p = (char*)d_ws;
    auto alloc = [&](size_t bytes) { void* r = (void*)p; p += (bytes + 255) & ~(size_t)255; return r; };
    float*  x     = (float*)alloc((size_t)TT * EE * 4);
    ushort* h_bf  = (ushort*)alloc((size_t)TT * EE * 2);
    ushort* qkvb  = (ushort*)alloc((size_t)TT * QKVN * 2);
    ushort* o_bf  = (ushort*)alloc((size_t)TT * EE * 2);
    ushort* ffb   = (ushort*)alloc((size_t)TT * FFD * 2);
    ushort* Wqkv  = (ushort*)alloc((size_t)QKVN * EE * 2);
    ushort* Wproj = (ushort*)alloc((size_t)EE * EE * 2);
    ushort* W1t   = (ushort*)alloc((size_t)FFD * EE * 2);
    ushort* W2t   = (ushort*)alloc((size_t)EE * FFD * 2);
    ushort* vTb   = (ushort*)alloc((size_t)HNN * HSS * TT * 2);
    // attn partials (2880 slots x 1056 fp32 = 12.2MB) alias the idle ffb buffer
    float* pbuf = (float*)ffb;

    // only batch 3 contributes to the output (logits[-1]; no cross-batch mixing)
    copy4_kernel<<<dim3((TT * EE / 4 + 255) / 256), dim3(256), 0, stream>>>(
        (float4*)x, (const float4*)(idx + (size_t)3 * TT * EE), TT * EE / 4);

    for (int l = 0; l < NLAYER; l++) {
        const size_t lw = (size_t)l;
        pack_qkv_kernel<<<dim3(12, 1, 36), dim3(256), 0, stream>>>(
            wq + lw * HNN * EE * HSS, wk + lw * HNN * EE * HSS, wv + lw * HNN * EE * HSS, Wqkv);
        pack_t_kernel<<<dim3(12, 12), dim3(256), 0, stream>>>(wproj + lw * EE * EE, EE, Wproj, EE);
        pack_t_kernel<<<dim3(12, 48), dim3(256), 0, stream>>>(w1 + lw * EE * FFD, FFD, W1t, EE);
        pack_t_kernel<<<dim3(48, 12), dim3(256), 0, stream>>>(w2 + lw * FFD * EE, EE, W2t, FFD);

        ln_kernel<<<dim3(TT), dim3(256), 0, stream>>>(x, ln1g + lw * EE, ln1b + lw * EE, h_bf);
        gemm_bf16<0><<<dim3(288), dim3(256), 0, stream>>>(
            h_bf, Wqkv, bq + lw * EE, bk + lw * EE, bv + lw * EE, nullptr, qkvb,
            QKVN, EE, 16, 1, EE);
        vtrans_kernel<<<dim3(768), dim3(256), 0, stream>>>(qkvb, vTb);
        attn_mfma<<<dim3(720), dim3(256), 0, stream>>>(qkvb, vTb, o_bf, pbuf);
        attn_combine<<<dim3(240), dim3(256), 0, stream>>>(pbuf, o_bf);
        gemm_bf16<1><<<dim3(384), dim3(256), 0, stream>>>(
            o_bf, Wproj, bproj + lw * EE, nullptr, nullptr, x, nullptr,
            EE, EE, 16, 4, 192);
        ln_kernel<<<dim3(TT), dim3(256), 0, stream>>>(x, ln2g + lw * EE, ln2b + lw * EE, h_bf);
        gemm_bf16<2><<<dim3(384), dim3(256), 0, stream>>>(
            h_bf, W1t, b1 + lw * FFD, nullptr, nullptr, nullptr, ffb,
            FFD, EE, 16, 1, EE);
        gemm_bf16<1><<<dim3(384), dim3(256), 0, stream>>>(
            ffb, W2t, b2 + lw * EE, nullptr, nullptr, x, nullptr,
            EE, FFD, 16, 4, 768);
    }

    ln_kernel<<<dim3(TT), dim3(256), 0, stream>>>(x, lnfg, lnfb, h_bf);
    pack_t_kernel<<<dim3(12, 48), dim3(256), 0, stream>>>(fw1, FFD, W1t, EE);
    pack_t_kernel<<<dim3(48, 12), dim3(256), 0, stream>>>(fw2, EE, W2t, FFD);
    gemm_bf16<2><<<dim3(384), dim3(256), 0, stream>>>(
        h_bf, W1t, fb1, nullptr, nullptr, nullptr, ffb, FFD, EE, 16, 1, EE);
    gemm_bf16<3><<<dim3(96), dim3(256), 0, stream>>>(
        ffb, W2t, fb2, nullptr, nullptr, x, nullptr, EE, FFD, 16, 1, FFD);
    head_kernel<<<dim3(TT), dim3(256), 0, stream>>>(x, hw, hb, out);
}

// Round 6
// 1681.199 us; speedup vs baseline: 1.1009x; 1.1009x over previous
//
#include <hip/hip_runtime.h>
#include <math.h>

#define TT 2048
#define EE 768
#define HNN 12
#define HSS 64
#define NLAYER 6
#define FFD 3072
#define QKVN 2304

constexpr float LN_EPS = 1e-5f;
constexpr float ATT_SCALE = 0.03608439182435161f; // 1/sqrt(768) (reference divides by sqrt(n_embed))
// log2-domain scale: exp(x*A) == exp2(x*A*log2e)
constexpr float ATT_SCALE_L2E = 0.03608439182435161f * 1.4426950408889634f;

typedef __attribute__((ext_vector_type(8))) short bf16x8;
typedef __attribute__((ext_vector_type(4))) float f32x4;

__device__ __forceinline__ ushort f2bf(float f) {
    union { float f; uint u; } c; c.f = f;
    const uint u = c.u;
    return (ushort)((u + 0x7fffu + ((u >> 16) & 1u)) >> 16);
}

__device__ __forceinline__ void gload16(const void* g, void* l) {
    __builtin_amdgcn_global_load_lds((const __attribute__((address_space(1))) void*)g,
                                     (__attribute__((address_space(3))) void*)l, 16, 0, 0);
}

// ---------------------------------------------------------------- copy ----
__global__ __launch_bounds__(256) void copy4_kernel(float4* __restrict__ dst,
                                                    const float4* __restrict__ src, int n4) {
    int i = blockIdx.x * 256 + threadIdx.x;
    if (i < n4) dst[i] = src[i];
}

// ----------------------------------------------------------- layernorm ----
__global__ __launch_bounds__(256) void ln_kernel(const float* __restrict__ in,
                                                 const float* __restrict__ g,
                                                 const float* __restrict__ b,
                                                 ushort* __restrict__ out) {
    __shared__ float red[8];
    const int t = blockIdx.x;
    const int tid = threadIdx.x;
    const float* row = in + (size_t)t * EE;
    float v0 = row[tid], v1 = row[tid + 256], v2 = row[tid + 512];
    float s = v0 + v1 + v2;
#pragma unroll
    for (int m = 1; m < 64; m <<= 1) s += __shfl_xor(s, m, 64);
    if ((tid & 63) == 0) red[tid >> 6] = s;
    __syncthreads();
    const float mean = (red[0] + red[1] + red[2] + red[3]) * (1.0f / EE);
    const float d0 = v0 - mean, d1 = v1 - mean, d2 = v2 - mean;
    float qq = d0 * d0 + d1 * d1 + d2 * d2;
#pragma unroll
    for (int m = 1; m < 64; m <<= 1) qq += __shfl_xor(qq, m, 64);
    __syncthreads();
    if ((tid & 63) == 0) red[tid >> 6] = qq;
    __syncthreads();
    const float var = (red[0] + red[1] + red[2] + red[3]) * (1.0f / EE);
    const float rstd = rsqrtf(var + LN_EPS);
    ushort* orow = out + (size_t)t * EE;
    orow[tid]       = f2bf(d0 * rstd * g[tid]       + b[tid]);
    orow[tid + 256] = f2bf(d1 * rstd * g[tid + 256] + b[tid + 256]);
    orow[tid + 512] = f2bf(d2 * rstd * g[tid + 512] + b[tid + 512]);
}

// --------------------------------------------------- weight pack (fp32->bf16^T)
__device__ __forceinline__ void transpose64(const float* __restrict__ src, int sld,
                                            ushort* __restrict__ dst, int dld,
                                            int k0, int n0, int tid) {
    __shared__ float t[64][68];
#pragma unroll
    for (int p = 0; p < 4; p++) {
        const int kr = p * 16 + (tid >> 4);
        *(float4*)&t[kr][(tid & 15) * 4] =
            *(const float4*)&src[(size_t)(k0 + kr) * sld + n0 + (tid & 15) * 4];
    }
    __syncthreads();
#pragma unroll
    for (int q = 0; q < 2; q++) {
        const int nl = q * 32 + (tid >> 3);
        const int kc = (tid & 7) * 8;
        ushort v[8];
#pragma unroll
        for (int j = 0; j < 8; j++) v[j] = f2bf(t[kc + j][nl]);
        uint4 o;
        o.x = (uint)v[0] | ((uint)v[1] << 16);
        o.y = (uint)v[2] | ((uint)v[3] << 16);
        o.z = (uint)v[4] | ((uint)v[5] << 16);
        o.w = (uint)v[6] | ((uint)v[7] << 16);
        *(uint4*)&dst[(size_t)(n0 + nl) * dld + k0 + kc] = o;
    }
}

__global__ __launch_bounds__(256) void pack_t_kernel(const float* __restrict__ src, int sld,
                                                     ushort* __restrict__ dst, int dld) {
    transpose64(src, sld, dst, dld, blockIdx.x * 64, blockIdx.y * 64, threadIdx.x);
}

__global__ __launch_bounds__(256) void pack_qkv_kernel(const float* __restrict__ wq,
                                                       const float* __restrict__ wk,
                                                       const float* __restrict__ wv,
                                                       ushort* __restrict__ dst) {
    const int z = blockIdx.z;
    const int which = z / HNN, hd = z % HNN;
    const float* src = (which == 0 ? wq : which == 1 ? wk : wv) + (size_t)hd * EE * HSS;
    ushort* d = dst + (size_t)(which * EE + hd * HSS) * EE;
    transpose64(src, HSS, d, EE, blockIdx.x * 64, 0, threadIdx.x);
}

// ------------------------------------------------------------ V transpose ----
__global__ __launch_bounds__(256) void vtrans_kernel(const ushort* __restrict__ qkv,
                                                     ushort* __restrict__ vT) {
    const int t = blockIdx.x * 256 + threadIdx.x;  // 0..196607
    const int d = t & 63;
    const int rest = t >> 6;
    const int tb = rest & 255;   // token block of 8
    const int hd = rest >> 8;    // 0..11
    const ushort* src = qkv + 1536 + hd * 64 + d;
    ushort v[8];
#pragma unroll
    for (int j = 0; j < 8; j++) v[j] = src[(size_t)(tb * 8 + j) * QKVN];
    uint4 o;
    o.x = (uint)v[0] | ((uint)v[1] << 16);
    o.y = (uint)v[2] | ((uint)v[3] << 16);
    o.z = (uint)v[4] | ((uint)v[5] << 16);
    o.w = (uint)v[6] | ((uint)v[7] << 16);
    *(uint4*)&vT[((size_t)hd * 64 + d) * TT + tb * 8] = o;
}

// ---------------------------------------------------------- bf16 GEMM ----
// (unchanged: XCD-contiguous remap, 2-phase pipeline, split-K EPI=1)
template <int EPI>
__global__ __launch_bounds__(256) void gemm_bf16(const ushort* __restrict__ A,
                                                 const ushort* __restrict__ Bt,
                                                 const float* __restrict__ b0,
                                                 const float* __restrict__ b1,
                                                 const float* __restrict__ b2,
                                                 float* __restrict__ outF,
                                                 ushort* __restrict__ outB,
                                                 int N, int K,
                                                 int nby, int KS, int Kslice) {
    __shared__ ushort Al[2][128 * 32];
    __shared__ ushort Bl[2][128 * 32];
    const int tid = threadIdx.x;
    const int wave = tid >> 6, lane = tid & 63;
    const int wm = wave >> 1, wn = wave & 1;
    const int l15 = lane & 15, q4 = lane >> 4;

    const int nwg = gridDim.x;
    const int wgid = ((int)blockIdx.x & 7) * (nwg >> 3) + ((int)blockIdx.x >> 3);
    const int mb = wgid % nby;
    const int t2 = wgid / nby;
    const int ks = t2 % KS;
    const int nb = t2 / KS;
    const int m0 = mb * 128, n0 = nb * 128;
    const int kbase = ks * Kslice;

    const int srow = lane >> 2;
    const int scb = (lane & 3) ^ ((lane >> 3) & 3);
    const ushort* Ag0 = A + (size_t)(m0 + wave * 16 + srow) * K + kbase + scb * 8;
    const ushort* Ag1 = Ag0 + (size_t)64 * K;
    const ushort* Bg0 = Bt + (size_t)(n0 + wave * 16 + srow) * K + kbase + scb * 8;
    const ushort* Bg1 = Bg0 + (size_t)64 * K;

    auto stage = [&](int buf, int kk) {
        const int off = kk * 32;
        gload16(Ag0 + off, &Al[buf][(wave * 16) * 32]);
        gload16(Ag1 + off, &Al[buf][(64 + wave * 16) * 32]);
        gload16(Bg0 + off, &Bl[buf][(wave * 16) * 32]);
        gload16(Bg1 + off, &Bl[buf][(64 + wave * 16) * 32]);
    };

    f32x4 acc[4][4];
#pragma unroll
    for (int i = 0; i < 4; i++)
#pragma unroll
        for (int j = 0; j < 4; j++) acc[i][j] = (f32x4){0.f, 0.f, 0.f, 0.f};

    stage(0, 0);
    __syncthreads();

    const int niter = Kslice >> 5;
    const int cq = (q4 ^ ((l15 >> 1) & 3)) * 8;

    for (int i = 0; i < niter; i++) {
        const int buf = i & 1;
        if (i + 1 < niter) stage(buf ^ 1, i + 1);
        bf16x8 af[4], bfr[4];
#pragma unroll
        for (int ii = 0; ii < 4; ii++)
            af[ii] = *(const bf16x8*)&Al[buf][(wm * 64 + ii * 16 + l15) * 32 + cq];
#pragma unroll
        for (int j = 0; j < 4; j++)
            bfr[j] = *(const bf16x8*)&Bl[buf][(wn * 64 + j * 16 + l15) * 32 + cq];
#pragma unroll
        for (int ii = 0; ii < 4; ii++)
#pragma unroll
            for (int j = 0; j < 4; j++)
                acc[ii][j] = __builtin_amdgcn_mfma_f32_16x16x32_bf16(af[ii], bfr[j], acc[ii][j], 0, 0, 0);
        __syncthreads();
    }

#pragma unroll
    for (int i = 0; i < 4; i++) {
        const int row = m0 + wm * 64 + i * 16 + q4 * 4;
#pragma unroll
        for (int j = 0; j < 4; j++) {
            const int col = n0 + wn * 64 + j * 16 + l15;
            float bias;
            if constexpr (EPI == 0)
                bias = (col < 768) ? b0[col] : (col < 1536 ? b1[col - 768] : b2[col - 1536]);
            else
                bias = (EPI == 1 && ks != 0) ? 0.f : b0[col];
#pragma unroll
            for (int r = 0; r < 4; r++) {
                const float v = acc[i][j][r] + bias;
                const size_t idx = (size_t)(row + r) * N + col;
                if constexpr (EPI == 0) {
                    outB[idx] = f2bf(v);
                } else if constexpr (EPI == 1) {
                    atomicAdd(&outF[idx], v);
                } else if constexpr (EPI == 2) {
                    outB[idx] = f2bf(0.5f * v * (1.0f + erff(v * 0.70710678118654752f)));
                } else {
                    outF[idx] = v;
                }
            }
        }
    }
}

// ----------------------------------------------------- MFMA attention ----
// R9: in-block key-split flash attention with LDS combine.
//  One block per (head, 16-row q-tile); the 4 waves split the tile's k-range
//  4 ways (per = ceil(nkt/4) <= 8 iters/wave -> balanced blocks; was 1..32).
//  Partials (m,l,O) merged in LDS after one barrier -- ZERO extra HBM traffic
//  (R5's global partials caused 182MB of write amplification under L2 thrash).
//  Head->XCD pinning restored (R4 map: FETCH 5.7MB).  6144 waves (~4/SIMD
//  resident) hide the per-iter latency chain.
//  Per-iter math unchanged: swapped QK^T (lane = one q-row), exp2 softmax,
//  rotation-swizzled Ps roundtrip, K reg-double-buffer, V stream from vT.
__global__ __launch_bounds__(256, 4) void attn_mfma(const ushort* __restrict__ qkv,
                                                    const ushort* __restrict__ vT,
                                                    ushort* __restrict__ o_bf) {
    __shared__ __align__(16) uint  Ps[4][16 * 36];
    __shared__ __align__(16) float Po[4][16 * 64];
    __shared__ float Pm[4][16];
    __shared__ float Pl[4][16];

    const int tid = threadIdx.x;
    const int wave = tid >> 6, lane = tid & 63;
    const int l15 = lane & 15, q4 = lane >> 4;

    // block decode: XCD x owns head x (+ half of head 8+(x>>1)); qi descending
    const int x = (int)blockIdx.x & 7, r = (int)blockIdx.x >> 3;
    int head, qi;
    if (r < 128) { head = x;            qi = 127 - r; }
    else         { head = 8 + (x >> 1); qi = 2 * (191 - r) + (x & 1); }
    const int nkt = (qi >> 2) + 1;       // k-tiles for this q-tile (1..32)
    const int per = (nkt + 3) >> 2;      // k-tiles per wave (1..8)
    const int kt0 = wave * per;
    const int kt1 = min(kt0 + per, nkt);
    const int qrow_g = qi * 16 + l15;

    // Q fragments (B-operand of swapped QK^T)
    const ushort* qp = qkv + (size_t)qrow_g * QKVN + head * 64;
    const bf16x8 qa0 = *(const bf16x8*)&qp[q4 * 8];
    const bf16x8 qa1 = *(const bf16x8*)&qp[32 + q4 * 8];

    // per-lane K / V^T bases
    const ushort* kbase = qkv + 768 + head * 64 + (size_t)l15 * QKVN + q4 * 8;
    const ushort* vbase = vT + ((size_t)head * 64 + l15) * TT + q4 * 8;

    float m_i = -1e30f, l_i = 0.f;
    f32x4 oacc[4];
#pragma unroll
    for (int n = 0; n < 4; n++) oacc[n] = (f32x4){0.f, 0.f, 0.f, 0.f};

    uint* psrow = &Ps[wave][l15 * 36];

    if (kt0 < kt1) {
        bf16x8 kA[8], kB[8], vC[8];
        // prologue: K tile kt0
        {
            const ushort* kp = kbase + (size_t)kt0 * 64 * QKVN;
#pragma unroll
            for (int n = 0; n < 4; n++)
#pragma unroll
                for (int kb = 0; kb < 2; kb++)
                    kA[n * 2 + kb] = *(const bf16x8*)(kp + (size_t)(n * 16) * QKVN + kb * 32);
        }

        auto body = [&](bf16x8* kc, bf16x8* kn, int kt) {
            // V^T for current tile (latency covered by QK^T + softmax)
            const ushort* vp = vbase + kt * 64;
#pragma unroll
            for (int n = 0; n < 4; n++)
#pragma unroll
                for (int kb = 0; kb < 2; kb++)
                    vC[n * 2 + kb] = *(const bf16x8*)(vp + (size_t)(n * 16) * TT + kb * 32);
            // prefetch K for next tile
            if (kt + 1 < kt1) {
                const ushort* kp = kbase + (size_t)(kt + 1) * 64 * QKVN;
#pragma unroll
                for (int n = 0; n < 4; n++)
#pragma unroll
                    for (int kb = 0; kb < 2; kb++)
                        kn[n * 2 + kb] = *(const bf16x8*)(kp + (size_t)(n * 16) * QKVN + kb * 32);
            }
            // S^T = K Q^T : lane -> q-row l15, keys n*16 + q4*4 + rr
            f32x4 s[4];
#pragma unroll
            for (int n = 0; n < 4; n++) {
                f32x4 a = (f32x4){0.f, 0.f, 0.f, 0.f};
                a = __builtin_amdgcn_mfma_f32_16x16x32_bf16(kc[n * 2], qa0, a, 0, 0, 0);
                a = __builtin_amdgcn_mfma_f32_16x16x32_bf16(kc[n * 2 + 1], qa1, a, 0, 0, 0);
                s[n] = a;
            }
            // scale into log2 domain + causal mask (global last tile only)
            float pe[16];
            const bool diag = (kt == nkt - 1);
#pragma unroll
            for (int n = 0; n < 4; n++) {
                const int k0 = kt * 64 + n * 16 + q4 * 4;
#pragma unroll
                for (int rr = 0; rr < 4; rr++) {
                    float xv = s[n][rr] * ATT_SCALE_L2E;
                    if (diag && (k0 + rr) > qrow_g) xv = -1e30f;
                    pe[n * 4 + rr] = xv;
                }
            }
            // row max: pairwise tree + 2 shfl
            float t8[8];
#pragma unroll
            for (int i = 0; i < 8; i++) t8[i] = fmaxf(pe[i], pe[i + 8]);
            float mx = fmaxf(fmaxf(fmaxf(t8[0], t8[4]), fmaxf(t8[1], t8[5])),
                             fmaxf(fmaxf(t8[2], t8[6]), fmaxf(t8[3], t8[7])));
            mx = fmaxf(mx, __shfl_xor(mx, 16, 64));
            mx = fmaxf(mx, __shfl_xor(mx, 32, 64));
            const float nm = fmaxf(m_i, mx);
            const float al = exp2f(m_i - nm);
#pragma unroll
            for (int i = 0; i < 16; i++) pe[i] = exp2f(pe[i] - nm);
            float s8[8];
#pragma unroll
            for (int i = 0; i < 8; i++) s8[i] = pe[i] + pe[i + 8];
            float rs = ((s8[0] + s8[4]) + (s8[1] + s8[5])) + ((s8[2] + s8[6]) + (s8[3] + s8[7]));
            rs += __shfl_xor(rs, 16, 64);
            rs += __shfl_xor(rs, 32, 64);
            l_i = l_i * al + rs;
            m_i = nm;
            // alpha for O-rows q4*4+rr
            float alr[4];
#pragma unroll
            for (int rr = 0; rr < 4; rr++) alr[rr] = __shfl(al, q4 * 4 + rr, 64);
#pragma unroll
            for (int n = 0; n < 4; n++) {
                oacc[n][0] *= alr[0];
                oacc[n][1] *= alr[1];
                oacc[n][2] *= alr[2];
                oacc[n][3] *= alr[3];
            }
            // P -> A-fragments via per-wave LDS, rotation-swizzled
#pragma unroll
            for (int n = 0; n < 4; n++) {
                uint2 d2;
                d2.x = (uint)f2bf(pe[n * 4 + 0]) | ((uint)f2bf(pe[n * 4 + 1]) << 16);
                d2.y = (uint)f2bf(pe[n * 4 + 2]) | ((uint)f2bf(pe[n * 4 + 3]) << 16);
                *(uint2*)&psrow[(8 * n + 2 * q4 + 4 * l15) & 31] = d2;
            }
            const bf16x8 pa0 = *(const bf16x8*)&psrow[(4 * q4 + 4 * l15) & 31];
            const bf16x8 pa1 = *(const bf16x8*)&psrow[(16 + 4 * q4 + 4 * l15) & 31];
            // O += P V
#pragma unroll
            for (int n = 0; n < 4; n++) {
                oacc[n] = __builtin_amdgcn_mfma_f32_16x16x32_bf16(pa0, vC[n * 2], oacc[n], 0, 0, 0);
                oacc[n] = __builtin_amdgcn_mfma_f32_16x16x32_bf16(pa1, vC[n * 2 + 1], oacc[n], 0, 0, 0);
            }
        };

        int kt = kt0;
        for (;;) {
            body(kA, kB, kt);
            if (++kt >= kt1) break;
            body(kB, kA, kt);
            if (++kt >= kt1) break;
        }
    }

    // partials -> LDS
#pragma unroll
    for (int n = 0; n < 4; n++)
#pragma unroll
        for (int rr = 0; rr < 4; rr++)
            Po[wave][(q4 * 4 + rr) * 64 + n * 16 + l15] = oacc[n][rr];
    if (q4 == 0) {
        Pm[wave][l15] = m_i;
        Pl[wave][l15] = l_i;
    }
    __syncthreads();

    // merge: thread -> (row = tid>>4, 4 cols at (tid&15)*4)
    const int row = tid >> 4;
    const int c4 = (tid & 15) * 4;
    const float m0 = Pm[0][row], m1 = Pm[1][row], m2 = Pm[2][row], m3 = Pm[3][row];
    const float M = fmaxf(fmaxf(m0, m1), fmaxf(m2, m3));
    const float w0 = exp2f(m0 - M), w1 = exp2f(m1 - M), w2 = exp2f(m2 - M), w3 = exp2f(m3 - M);
    const float L = w0 * Pl[0][row] + w1 * Pl[1][row] + w2 * Pl[2][row] + w3 * Pl[3][row];
    const f32x4 o0 = *(const f32x4*)&Po[0][row * 64 + c4];
    const f32x4 o1 = *(const f32x4*)&Po[1][row * 64 + c4];
    const f32x4 o2 = *(const f32x4*)&Po[2][row * 64 + c4];
    const f32x4 o3 = *(const f32x4*)&Po[3][row * 64 + c4];
    const float rl = 1.0f / L;
    uint2 ow;
    {
        const float v0 = (w0 * o0[0] + w1 * o1[0] + w2 * o2[0] + w3 * o3[0]) * rl;
        const float v1 = (w0 * o0[1] + w1 * o1[1] + w2 * o2[1] + w3 * o3[1]) * rl;
        const float v2 = (w0 * o0[2] + w1 * o1[2] + w2 * o2[2] + w3 * o3[2]) * rl;
        const float v3 = (w0 * o0[3] + w1 * o1[3] + w2 * o2[3] + w3 * o3[3]) * rl;
        ow.x = (uint)f2bf(v0) | ((uint)f2bf(v1) << 16);
        ow.y = (uint)f2bf(v2) | ((uint)f2bf(v3) << 16);
    }
    *(uint2*)&o_bf[(size_t)(qi * 16 + row) * EE + head * 64 + c4] = ow;
}

// ---------------------------------------------------------------- head ----
__global__ __launch_bounds__(256) void head_kernel(const float* __restrict__ x,
                                                   const float* __restrict__ hw,
                                                   const float* __restrict__ hb,
                                                   float* __restrict__ out) {
    __shared__ float red[8];
    const int t = blockIdx.x, tid = threadIdx.x;
    const float* row = x + (size_t)t * EE;
    float s = row[tid] * hw[tid] + row[tid + 256] * hw[tid + 256] + row[tid + 512] * hw[tid + 512];
#pragma unroll
    for (int m = 1; m < 64; m <<= 1) s += __shfl_xor(s, m, 64);
    if ((tid & 63) == 0) red[tid >> 6] = s;
    __syncthreads();
    if (tid == 0) out[t] = red[0] + red[1] + red[2] + red[3] + hb[0];
}

// -------------------------------------------------------------- launch ----
extern "C" void kernel_launch(void* const* d_in, const int* in_sizes, int n_in,
                              void* d_out, int out_size, void* d_ws, size_t ws_size,
                              hipStream_t stream) {
    const float* idx   = (const float*)d_in[0];
    const float* wq    = (const float*)d_in[2];
    const float* bq    = (const float*)d_in[3];
    const float* wk    = (const float*)d_in[4];
    const float* bk    = (const float*)d_in[5];
    const float* wv    = (const float*)d_in[6];
    const float* bv    = (const float*)d_in[7];
    const float* wproj = (const float*)d_in[8];
    const float* bproj = (const float*)d_in[9];
    const float* ln1g  = (const float*)d_in[10];
    const float* ln1b  = (const float*)d_in[11];
    const float* ln2g  = (const float*)d_in[12];
    const float* ln2b  = (const float*)d_in[13];
    const float* w1    = (const float*)d_in[14];
    const float* b1    = (const float*)d_in[15];
    const float* w2    = (const float*)d_in[16];
    const float* b2    = (const float*)d_in[17];
    const float* lnfg  = (const float*)d_in[18];
    const float* lnfb  = (const float*)d_in[19];
    const float* fw1   = (const float*)d_in[20];
    const float* fb1   = (const float*)d_in[21];
    const float* fw2   = (const float*)d_in[22];
    const float* fb2   = (const float*)d_in[23];
    const float* hw    = (const float*)d_in[24];
    const float* hb    = (const float*)d_in[25];
    float* out = (float*)d_out;

    // ---- workspace carve (~50 MB) ----
    char* p = (char*)d_ws;
    auto alloc = [&](size_t bytes) { void* r = (void*)p; p += (bytes + 255) & ~(size_t)255; return r; };
    float*  x     = (float*)alloc((size_t)TT * EE * 4);
    ushort* h_bf  = (ushort*)alloc((size_t)TT * EE * 2);
    ushort* qkvb  = (ushort*)alloc((size_t)TT * QKVN * 2);
    ushort* o_bf  = (ushort*)alloc((size_t)TT * EE * 2);
    ushort* ffb   = (ushort*)alloc((size_t)TT * FFD * 2);
    ushort* Wqkv  = (ushort*)alloc((size_t)QKVN * EE * 2);
    ushort* Wproj = (ushort*)alloc((size_t)EE * EE * 2);
    ushort* W1t   = (ushort*)alloc((size_t)FFD * EE * 2);
    ushort* W2t   = (ushort*)alloc((size_t)EE * FFD * 2);
    ushort* vTb   = (ushort*)alloc((size_t)HNN * HSS * TT * 2);

    // only batch 3 contributes to the output (logits[-1]; no cross-batch mixing)
    copy4_kernel<<<dim3((TT * EE / 4 + 255) / 256), dim3(256), 0, stream>>>(
        (float4*)x, (const float4*)(idx + (size_t)3 * TT * EE), TT * EE / 4);

    for (int l = 0; l < NLAYER; l++) {
        const size_t lw = (size_t)l;
        pack_qkv_kernel<<<dim3(12, 1, 36), dim3(256), 0, stream>>>(
            wq + lw * HNN * EE * HSS, wk + lw * HNN * EE * HSS, wv + lw * HNN * EE * HSS, Wqkv);
        pack_t_kernel<<<dim3(12, 12), dim3(256), 0, stream>>>(wproj + lw * EE * EE, EE, Wproj, EE);
        pack_t_kernel<<<dim3(12, 48), dim3(256), 0, stream>>>(w1 + lw * EE * FFD, FFD, W1t, EE);
        pack_t_kernel<<<dim3(48, 12), dim3(256), 0, stream>>>(w2 + lw * FFD * EE, EE, W2t, FFD);

        ln_kernel<<<dim3(TT), dim3(256), 0, stream>>>(x, ln1g + lw * EE, ln1b + lw * EE, h_bf);
        gemm_bf16<0><<<dim3(288), dim3(256), 0, stream>>>(
            h_bf, Wqkv, bq + lw * EE, bk + lw * EE, bv + lw * EE, nullptr, qkvb,
            QKVN, EE, 16, 1, EE);
        vtrans_kernel<<<dim3(768), dim3(256), 0, stream>>>(qkvb, vTb);
        attn_mfma<<<dim3(1536), dim3(256), 0, stream>>>(qkvb, vTb, o_bf);
        gemm_bf16<1><<<dim3(384), dim3(256), 0, stream>>>(
            o_bf, Wproj, bproj + lw * EE, nullptr, nullptr, x, nullptr,
            EE, EE, 16, 4, 192);
        ln_kernel<<<dim3(TT), dim3(256), 0, stream>>>(x, ln2g + lw * EE, ln2b + lw * EE, h_bf);
        gemm_bf16<2><<<dim3(384), dim3(256), 0, stream>>>(
            h_bf, W1t, b1 + lw * FFD, nullptr, nullptr, nullptr, ffb,
            FFD, EE, 16, 1, EE);
        gemm_bf16<1><<<dim3(384), dim3(256), 0, stream>>>(
            ffb, W2t, b2 + lw * EE, nullptr, nullptr, x, nullptr,
            EE, FFD, 16, 4, 768);
    }

    ln_kernel<<<dim3(TT), dim3(256), 0, stream>>>(x, lnfg, lnfb, h_bf);
    pack_t_kernel<<<dim3(12, 48), dim3(256), 0, stream>>>(fw1, FFD, W1t, EE);
    pack_t_kernel<<<dim3(48, 12), dim3(256), 0, stream>>>(fw2, EE, W2t, FFD);
    gemm_bf16<2><<<dim3(384), dim3(256), 0, stream>>>(
        h_bf, W1t, fb1, nullptr, nullptr, nullptr, ffb, FFD, EE, 16, 1, EE);
    gemm_bf16<3><<<dim3(96), dim3(256), 0, stream>>>(
        ffb, W2t, fb2, nullptr, nullptr, x, nullptr, EE, FFD, 16, 1, FFD);
    head_kernel<<<dim3(TT), dim3(256), 0, stream>>>(x, hw, hb, out);
}

// Round 7
// 1500.718 us; speedup vs baseline: 1.2333x; 1.1203x over previous
//
#include <hip/hip_runtime.h>
#include <math.h>

#define TT 2048
#define EE 768
#define HNN 12
#define HSS 64
#define NLAYER 6
#define FFD 3072
#define QKVN 2304

constexpr float LN_EPS = 1e-5f;
constexpr float ATT_SCALE = 0.03608439182435161f; // 1/sqrt(768) (reference divides by sqrt(n_embed))
// log2-domain scale: exp(x*A) == exp2(x*A*log2e)
constexpr float ATT_SCALE_L2E = 0.03608439182435161f * 1.4426950408889634f;

typedef __attribute__((ext_vector_type(8))) short bf16x8;
typedef __attribute__((ext_vector_type(4))) float f32x4;

__device__ __forceinline__ ushort f2bf(float f) {
    union { float f; uint u; } c; c.f = f;
    const uint u = c.u;
    return (ushort)((u + 0x7fffu + ((u >> 16) & 1u)) >> 16);
}

__device__ __forceinline__ void gload16(const void* g, void* l) {
    __builtin_amdgcn_global_load_lds((const __attribute__((address_space(1))) void*)g,
                                     (__attribute__((address_space(3))) void*)l, 16, 0, 0);
}

// ---------------------------------------------------------------- copy ----
__global__ __launch_bounds__(256) void copy4_kernel(float4* __restrict__ dst,
                                                    const float4* __restrict__ src, int n4) {
    int i = blockIdx.x * 256 + threadIdx.x;
    if (i < n4) dst[i] = src[i];
}

// ----------------------------------------------------------- layernorm ----
__global__ __launch_bounds__(256) void ln_kernel(const float* __restrict__ in,
                                                 const float* __restrict__ g,
                                                 const float* __restrict__ b,
                                                 ushort* __restrict__ out) {
    __shared__ float red[8];
    const int t = blockIdx.x;
    const int tid = threadIdx.x;
    const float* row = in + (size_t)t * EE;
    float v0 = row[tid], v1 = row[tid + 256], v2 = row[tid + 512];
    float s = v0 + v1 + v2;
#pragma unroll
    for (int m = 1; m < 64; m <<= 1) s += __shfl_xor(s, m, 64);
    if ((tid & 63) == 0) red[tid >> 6] = s;
    __syncthreads();
    const float mean = (red[0] + red[1] + red[2] + red[3]) * (1.0f / EE);
    const float d0 = v0 - mean, d1 = v1 - mean, d2 = v2 - mean;
    float qq = d0 * d0 + d1 * d1 + d2 * d2;
#pragma unroll
    for (int m = 1; m < 64; m <<= 1) qq += __shfl_xor(qq, m, 64);
    __syncthreads();
    if ((tid & 63) == 0) red[tid >> 6] = qq;
    __syncthreads();
    const float var = (red[0] + red[1] + red[2] + red[3]) * (1.0f / EE);
    const float rstd = rsqrtf(var + LN_EPS);
    ushort* orow = out + (size_t)t * EE;
    orow[tid]       = f2bf(d0 * rstd * g[tid]       + b[tid]);
    orow[tid + 256] = f2bf(d1 * rstd * g[tid + 256] + b[tid + 256]);
    orow[tid + 512] = f2bf(d2 * rstd * g[tid + 512] + b[tid + 512]);
}

// --------------------------------------------------- weight pack (fp32->bf16^T)
__device__ __forceinline__ void transpose64(const float* __restrict__ src, int sld,
                                            ushort* __restrict__ dst, int dld,
                                            int k0, int n0, int tid) {
    __shared__ float t[64][68];
#pragma unroll
    for (int p = 0; p < 4; p++) {
        const int kr = p * 16 + (tid >> 4);
        *(float4*)&t[kr][(tid & 15) * 4] =
            *(const float4*)&src[(size_t)(k0 + kr) * sld + n0 + (tid & 15) * 4];
    }
    __syncthreads();
#pragma unroll
    for (int q = 0; q < 2; q++) {
        const int nl = q * 32 + (tid >> 3);
        const int kc = (tid & 7) * 8;
        ushort v[8];
#pragma unroll
        for (int j = 0; j < 8; j++) v[j] = f2bf(t[kc + j][nl]);
        uint4 o;
        o.x = (uint)v[0] | ((uint)v[1] << 16);
        o.y = (uint)v[2] | ((uint)v[3] << 16);
        o.z = (uint)v[4] | ((uint)v[5] << 16);
        o.w = (uint)v[6] | ((uint)v[7] << 16);
        *(uint4*)&dst[(size_t)(n0 + nl) * dld + k0 + kc] = o;
    }
}

__global__ __launch_bounds__(256) void pack_t_kernel(const float* __restrict__ src, int sld,
                                                     ushort* __restrict__ dst, int dld) {
    transpose64(src, sld, dst, dld, blockIdx.x * 64, blockIdx.y * 64, threadIdx.x);
}

__global__ __launch_bounds__(256) void pack_qkv_kernel(const float* __restrict__ wq,
                                                       const float* __restrict__ wk,
                                                       const float* __restrict__ wv,
                                                       ushort* __restrict__ dst) {
    const int z = blockIdx.z;
    const int which = z / HNN, hd = z % HNN;
    const float* src = (which == 0 ? wq : which == 1 ? wk : wv) + (size_t)hd * EE * HSS;
    ushort* d = dst + (size_t)(which * EE + hd * HSS) * EE;
    transpose64(src, HSS, d, EE, blockIdx.x * 64, 0, threadIdx.x);
}

// ------------------------------------------------------------ V transpose ----
__global__ __launch_bounds__(256) void vtrans_kernel(const ushort* __restrict__ qkv,
                                                     ushort* __restrict__ vT) {
    const int t = blockIdx.x * 256 + threadIdx.x;  // 0..196607
    const int d = t & 63;
    const int rest = t >> 6;
    const int tb = rest & 255;   // token block of 8
    const int hd = rest >> 8;    // 0..11
    const ushort* src = qkv + 1536 + hd * 64 + d;
    ushort v[8];
#pragma unroll
    for (int j = 0; j < 8; j++) v[j] = src[(size_t)(tb * 8 + j) * QKVN];
    uint4 o;
    o.x = (uint)v[0] | ((uint)v[1] << 16);
    o.y = (uint)v[2] | ((uint)v[3] << 16);
    o.z = (uint)v[4] | ((uint)v[5] << 16);
    o.w = (uint)v[6] | ((uint)v[7] << 16);
    *(uint4*)&vT[((size_t)hd * 64 + d) * TT + tb * 8] = o;
}

// ---------------------------------------------------------- bf16 GEMM ----
// (unchanged: XCD-contiguous remap, 2-phase pipeline, split-K EPI=1)
template <int EPI>
__global__ __launch_bounds__(256) void gemm_bf16(const ushort* __restrict__ A,
                                                 const ushort* __restrict__ Bt,
                                                 const float* __restrict__ b0,
                                                 const float* __restrict__ b1,
                                                 const float* __restrict__ b2,
                                                 float* __restrict__ outF,
                                                 ushort* __restrict__ outB,
                                                 int N, int K,
                                                 int nby, int KS, int Kslice) {
    __shared__ ushort Al[2][128 * 32];
    __shared__ ushort Bl[2][128 * 32];
    const int tid = threadIdx.x;
    const int wave = tid >> 6, lane = tid & 63;
    const int wm = wave >> 1, wn = wave & 1;
    const int l15 = lane & 15, q4 = lane >> 4;

    const int nwg = gridDim.x;
    const int wgid = ((int)blockIdx.x & 7) * (nwg >> 3) + ((int)blockIdx.x >> 3);
    const int mb = wgid % nby;
    const int t2 = wgid / nby;
    const int ks = t2 % KS;
    const int nb = t2 / KS;
    const int m0 = mb * 128, n0 = nb * 128;
    const int kbase = ks * Kslice;

    const int srow = lane >> 2;
    const int scb = (lane & 3) ^ ((lane >> 3) & 3);
    const ushort* Ag0 = A + (size_t)(m0 + wave * 16 + srow) * K + kbase + scb * 8;
    const ushort* Ag1 = Ag0 + (size_t)64 * K;
    const ushort* Bg0 = Bt + (size_t)(n0 + wave * 16 + srow) * K + kbase + scb * 8;
    const ushort* Bg1 = Bg0 + (size_t)64 * K;

    auto stage = [&](int buf, int kk) {
        const int off = kk * 32;
        gload16(Ag0 + off, &Al[buf][(wave * 16) * 32]);
        gload16(Ag1 + off, &Al[buf][(64 + wave * 16) * 32]);
        gload16(Bg0 + off, &Bl[buf][(wave * 16) * 32]);
        gload16(Bg1 + off, &Bl[buf][(64 + wave * 16) * 32]);
    };

    f32x4 acc[4][4];
#pragma unroll
    for (int i = 0; i < 4; i++)
#pragma unroll
        for (int j = 0; j < 4; j++) acc[i][j] = (f32x4){0.f, 0.f, 0.f, 0.f};

    stage(0, 0);
    __syncthreads();

    const int niter = Kslice >> 5;
    const int cq = (q4 ^ ((l15 >> 1) & 3)) * 8;

    for (int i = 0; i < niter; i++) {
        const int buf = i & 1;
        if (i + 1 < niter) stage(buf ^ 1, i + 1);
        bf16x8 af[4], bfr[4];
#pragma unroll
        for (int ii = 0; ii < 4; ii++)
            af[ii] = *(const bf16x8*)&Al[buf][(wm * 64 + ii * 16 + l15) * 32 + cq];
#pragma unroll
        for (int j = 0; j < 4; j++)
            bfr[j] = *(const bf16x8*)&Bl[buf][(wn * 64 + j * 16 + l15) * 32 + cq];
#pragma unroll
        for (int ii = 0; ii < 4; ii++)
#pragma unroll
            for (int j = 0; j < 4; j++)
                acc[ii][j] = __builtin_amdgcn_mfma_f32_16x16x32_bf16(af[ii], bfr[j], acc[ii][j], 0, 0, 0);
        __syncthreads();
    }

#pragma unroll
    for (int i = 0; i < 4; i++) {
        const int row = m0 + wm * 64 + i * 16 + q4 * 4;
#pragma unroll
        for (int j = 0; j < 4; j++) {
            const int col = n0 + wn * 64 + j * 16 + l15;
            float bias;
            if constexpr (EPI == 0)
                bias = (col < 768) ? b0[col] : (col < 1536 ? b1[col - 768] : b2[col - 1536]);
            else
                bias = (EPI == 1 && ks != 0) ? 0.f : b0[col];
#pragma unroll
            for (int r = 0; r < 4; r++) {
                const float v = acc[i][j][r] + bias;
                const size_t idx = (size_t)(row + r) * N + col;
                if constexpr (EPI == 0) {
                    outB[idx] = f2bf(v);
                } else if constexpr (EPI == 1) {
                    atomicAdd(&outF[idx], v);
                } else if constexpr (EPI == 2) {
                    outB[idx] = f2bf(0.5f * v * (1.0f + erff(v * 0.70710678118654752f)));
                } else {
                    outF[idx] = v;
                }
            }
        }
    }
}

// ----------------------------------------------------- MFMA attention ----
// R9 structure + R10 fix.
//  R10: __launch_bounds__(256, 2) NOT (256, 4).  The (256,4) bound capped the
//  allocator at 64 VGPRs; live state is ~135 (kA/kB/vC = 96 alone) -> ~70
//  VGPRs spilled to scratch, ~16KB/wave/iter of scratch traffic = 267MB HBM
//  per dispatch (the mysterious WRITE_SIZE 178MB in R5/R6 -- NOT partials).
//  At (256,2) the same code compiles to ~92-110 VGPR, zero spill (R4 proof).
//  Structure (R9): one block per (head, q-tile); 4 waves split the k-range
//  (per = ceil(nkt/4) <= 8 iters/wave, balanced); partials merged in LDS.
//  Head->XCD pinning; swapped QK^T; exp2 softmax; rotation-swizzled Ps;
//  K reg-double-buffer; V streamed from pre-transposed vT.
__global__ __launch_bounds__(256, 2) void attn_mfma(const ushort* __restrict__ qkv,
                                                    const ushort* __restrict__ vT,
                                                    ushort* __restrict__ o_bf) {
    __shared__ __align__(16) uint  Ps[4][16 * 36];
    __shared__ __align__(16) float Po[4][16 * 64];
    __shared__ float Pm[4][16];
    __shared__ float Pl[4][16];

    const int tid = threadIdx.x;
    const int wave = tid >> 6, lane = tid & 63;
    const int l15 = lane & 15, q4 = lane >> 4;

    // block decode: XCD x owns head x (+ half of head 8+(x>>1)); qi descending
    const int x = (int)blockIdx.x & 7, r = (int)blockIdx.x >> 3;
    int head, qi;
    if (r < 128) { head = x;            qi = 127 - r; }
    else         { head = 8 + (x >> 1); qi = 2 * (191 - r) + (x & 1); }
    const int nkt = (qi >> 2) + 1;       // k-tiles for this q-tile (1..32)
    const int per = (nkt + 3) >> 2;      // k-tiles per wave (1..8)
    const int kt0 = wave * per;
    const int kt1 = min(kt0 + per, nkt);
    const int qrow_g = qi * 16 + l15;

    // Q fragments (B-operand of swapped QK^T)
    const ushort* qp = qkv + (size_t)qrow_g * QKVN + head * 64;
    const bf16x8 qa0 = *(const bf16x8*)&qp[q4 * 8];
    const bf16x8 qa1 = *(const bf16x8*)&qp[32 + q4 * 8];

    // per-lane K / V^T bases
    const ushort* kbase = qkv + 768 + head * 64 + (size_t)l15 * QKVN + q4 * 8;
    const ushort* vbase = vT + ((size_t)head * 64 + l15) * TT + q4 * 8;

    float m_i = -1e30f, l_i = 0.f;
    f32x4 oacc[4];
#pragma unroll
    for (int n = 0; n < 4; n++) oacc[n] = (f32x4){0.f, 0.f, 0.f, 0.f};

    uint* psrow = &Ps[wave][l15 * 36];

    if (kt0 < kt1) {
        bf16x8 kA[8], kB[8], vC[8];
        // prologue: K tile kt0
        {
            const ushort* kp = kbase + (size_t)kt0 * 64 * QKVN;
#pragma unroll
            for (int n = 0; n < 4; n++)
#pragma unroll
                for (int kb = 0; kb < 2; kb++)
                    kA[n * 2 + kb] = *(const bf16x8*)(kp + (size_t)(n * 16) * QKVN + kb * 32);
        }

        auto body = [&](bf16x8* kc, bf16x8* kn, int kt) {
            // V^T for current tile (latency covered by QK^T + softmax)
            const ushort* vp = vbase + kt * 64;
#pragma unroll
            for (int n = 0; n < 4; n++)
#pragma unroll
                for (int kb = 0; kb < 2; kb++)
                    vC[n * 2 + kb] = *(const bf16x8*)(vp + (size_t)(n * 16) * TT + kb * 32);
            // prefetch K for next tile
            if (kt + 1 < kt1) {
                const ushort* kp = kbase + (size_t)(kt + 1) * 64 * QKVN;
#pragma unroll
                for (int n = 0; n < 4; n++)
#pragma unroll
                    for (int kb = 0; kb < 2; kb++)
                        kn[n * 2 + kb] = *(const bf16x8*)(kp + (size_t)(n * 16) * QKVN + kb * 32);
            }
            // S^T = K Q^T : lane -> q-row l15, keys n*16 + q4*4 + rr
            f32x4 s[4];
#pragma unroll
            for (int n = 0; n < 4; n++) {
                f32x4 a = (f32x4){0.f, 0.f, 0.f, 0.f};
                a = __builtin_amdgcn_mfma_f32_16x16x32_bf16(kc[n * 2], qa0, a, 0, 0, 0);
                a = __builtin_amdgcn_mfma_f32_16x16x32_bf16(kc[n * 2 + 1], qa1, a, 0, 0, 0);
                s[n] = a;
            }
            // scale into log2 domain + causal mask (global last tile only)
            float pe[16];
            const bool diag = (kt == nkt - 1);
#pragma unroll
            for (int n = 0; n < 4; n++) {
                const int k0 = kt * 64 + n * 16 + q4 * 4;
#pragma unroll
                for (int rr = 0; rr < 4; rr++) {
                    float xv = s[n][rr] * ATT_SCALE_L2E;
                    if (diag && (k0 + rr) > qrow_g) xv = -1e30f;
                    pe[n * 4 + rr] = xv;
                }
            }
            // row max: pairwise tree + 2 shfl
            float t8[8];
#pragma unroll
            for (int i = 0; i < 8; i++) t8[i] = fmaxf(pe[i], pe[i + 8]);
            float mx = fmaxf(fmaxf(fmaxf(t8[0], t8[4]), fmaxf(t8[1], t8[5])),
                             fmaxf(fmaxf(t8[2], t8[6]), fmaxf(t8[3], t8[7])));
            mx = fmaxf(mx, __shfl_xor(mx, 16, 64));
            mx = fmaxf(mx, __shfl_xor(mx, 32, 64));
            const float nm = fmaxf(m_i, mx);
            const float al = exp2f(m_i - nm);
#pragma unroll
            for (int i = 0; i < 16; i++) pe[i] = exp2f(pe[i] - nm);
            float s8[8];
#pragma unroll
            for (int i = 0; i < 8; i++) s8[i] = pe[i] + pe[i + 8];
            float rs = ((s8[0] + s8[4]) + (s8[1] + s8[5])) + ((s8[2] + s8[6]) + (s8[3] + s8[7]));
            rs += __shfl_xor(rs, 16, 64);
            rs += __shfl_xor(rs, 32, 64);
            l_i = l_i * al + rs;
            m_i = nm;
            // alpha for O-rows q4*4+rr
            float alr[4];
#pragma unroll
            for (int rr = 0; rr < 4; rr++) alr[rr] = __shfl(al, q4 * 4 + rr, 64);
#pragma unroll
            for (int n = 0; n < 4; n++) {
                oacc[n][0] *= alr[0];
                oacc[n][1] *= alr[1];
                oacc[n][2] *= alr[2];
                oacc[n][3] *= alr[3];
            }
            // P -> A-fragments via per-wave LDS, rotation-swizzled
#pragma unroll
            for (int n = 0; n < 4; n++) {
                uint2 d2;
                d2.x = (uint)f2bf(pe[n * 4 + 0]) | ((uint)f2bf(pe[n * 4 + 1]) << 16);
                d2.y = (uint)f2bf(pe[n * 4 + 2]) | ((uint)f2bf(pe[n * 4 + 3]) << 16);
                *(uint2*)&psrow[(8 * n + 2 * q4 + 4 * l15) & 31] = d2;
            }
            const bf16x8 pa0 = *(const bf16x8*)&psrow[(4 * q4 + 4 * l15) & 31];
            const bf16x8 pa1 = *(const bf16x8*)&psrow[(16 + 4 * q4 + 4 * l15) & 31];
            // O += P V
#pragma unroll
            for (int n = 0; n < 4; n++) {
                oacc[n] = __builtin_amdgcn_mfma_f32_16x16x32_bf16(pa0, vC[n * 2], oacc[n], 0, 0, 0);
                oacc[n] = __builtin_amdgcn_mfma_f32_16x16x32_bf16(pa1, vC[n * 2 + 1], oacc[n], 0, 0, 0);
            }
        };

        int kt = kt0;
        for (;;) {
            body(kA, kB, kt);
            if (++kt >= kt1) break;
            body(kB, kA, kt);
            if (++kt >= kt1) break;
        }
    }

    // partials -> LDS
#pragma unroll
    for (int n = 0; n < 4; n++)
#pragma unroll
        for (int rr = 0; rr < 4; rr++)
            Po[wave][(q4 * 4 + rr) * 64 + n * 16 + l15] = oacc[n][rr];
    if (q4 == 0) {
        Pm[wave][l15] = m_i;
        Pl[wave][l15] = l_i;
    }
    __syncthreads();

    // merge: thread -> (row = tid>>4, 4 cols at (tid&15)*4)
    const int row = tid >> 4;
    const int c4 = (tid & 15) * 4;
    const float m0 = Pm[0][row], m1 = Pm[1][row], m2 = Pm[2][row], m3 = Pm[3][row];
    const float M = fmaxf(fmaxf(m0, m1), fmaxf(m2, m3));
    const float w0 = exp2f(m0 - M), w1 = exp2f(m1 - M), w2 = exp2f(m2 - M), w3 = exp2f(m3 - M);
    const float L = w0 * Pl[0][row] + w1 * Pl[1][row] + w2 * Pl[2][row] + w3 * Pl[3][row];
    const f32x4 o0 = *(const f32x4*)&Po[0][row * 64 + c4];
    const f32x4 o1 = *(const f32x4*)&Po[1][row * 64 + c4];
    const f32x4 o2 = *(const f32x4*)&Po[2][row * 64 + c4];
    const f32x4 o3 = *(const f32x4*)&Po[3][row * 64 + c4];
    const float rl = 1.0f / L;
    uint2 ow;
    {
        const float v0 = (w0 * o0[0] + w1 * o1[0] + w2 * o2[0] + w3 * o3[0]) * rl;
        const float v1 = (w0 * o0[1] + w1 * o1[1] + w2 * o2[1] + w3 * o3[1]) * rl;
        const float v2 = (w0 * o0[2] + w1 * o1[2] + w2 * o2[2] + w3 * o3[2]) * rl;
        const float v3 = (w0 * o0[3] + w1 * o1[3] + w2 * o2[3] + w3 * o3[3]) * rl;
        ow.x = (uint)f2bf(v0) | ((uint)f2bf(v1) << 16);
        ow.y = (uint)f2bf(v2) | ((uint)f2bf(v3) << 16);
    }
    *(uint2*)&o_bf[(size_t)(qi * 16 + row) * EE + head * 64 + c4] = ow;
}

// ---------------------------------------------------------------- head ----
__global__ __launch_bounds__(256) void head_kernel(const float* __restrict__ x,
                                                   const float* __restrict__ hw,
                                                   const float* __restrict__ hb,
                                                   float* __restrict__ out) {
    __shared__ float red[8];
    const int t = blockIdx.x, tid = threadIdx.x;
    const float* row = x + (size_t)t * EE;
    float s = row[tid] * hw[tid] + row[tid + 256] * hw[tid + 256] + row[tid + 512] * hw[tid + 512];
#pragma unroll
    for (int m = 1; m < 64; m <<= 1) s += __shfl_xor(s, m, 64);
    if ((tid & 63) == 0) red[tid >> 6] = s;
    __syncthreads();
    if (tid == 0) out[t] = red[0] + red[1] + red[2] + red[3] + hb[0];
}

// -------------------------------------------------------------- launch ----
extern "C" void kernel_launch(void* const* d_in, const int* in_sizes, int n_in,
                              void* d_out, int out_size, void* d_ws, size_t ws_size,
                              hipStream_t stream) {
    const float* idx   = (const float*)d_in[0];
    const float* wq    = (const float*)d_in[2];
    const float* bq    = (const float*)d_in[3];
    const float* wk    = (const float*)d_in[4];
    const float* bk    = (const float*)d_in[5];
    const float* wv    = (const float*)d_in[6];
    const float* bv    = (const float*)d_in[7];
    const float* wproj = (const float*)d_in[8];
    const float* bproj = (const float*)d_in[9];
    const float* ln1g  = (const float*)d_in[10];
    const float* ln1b  = (const float*)d_in[11];
    const float* ln2g  = (const float*)d_in[12];
    const float* ln2b  = (const float*)d_in[13];
    const float* w1    = (const float*)d_in[14];
    const float* b1    = (const float*)d_in[15];
    const float* w2    = (const float*)d_in[16];
    const float* b2    = (const float*)d_in[17];
    const float* lnfg  = (const float*)d_in[18];
    const float* lnfb  = (const float*)d_in[19];
    const float* fw1   = (const float*)d_in[20];
    const float* fb1   = (const float*)d_in[21];
    const float* fw2   = (const float*)d_in[22];
    const float* fb2   = (const float*)d_in[23];
    const float* hw    = (const float*)d_in[24];
    const float* hb    = (const float*)d_in[25];
    float* out = (float*)d_out;

    // ---- workspace carve (~50 MB) ----
    char* p = (char*)d_ws;
    auto alloc = [&](size_t bytes) { void* r = (void*)p; p += (bytes + 255) & ~(size_t)255; return r; };
    float*  x     = (float*)alloc((size_t)TT * EE * 4);
    ushort* h_bf  = (ushort*)alloc((size_t)TT * EE * 2);
    ushort* qkvb  = (ushort*)alloc((size_t)TT * QKVN * 2);
    ushort* o_bf  = (ushort*)alloc((size_t)TT * EE * 2);
    ushort* ffb   = (ushort*)alloc((size_t)TT * FFD * 2);
    ushort* Wqkv  = (ushort*)alloc((size_t)QKVN * EE * 2);
    ushort* Wproj = (ushort*)alloc((size_t)EE * EE * 2);
    ushort* W1t   = (ushort*)alloc((size_t)FFD * EE * 2);
    ushort* W2t   = (ushort*)alloc((size_t)EE * FFD * 2);
    ushort* vTb   = (ushort*)alloc((size_t)HNN * HSS * TT * 2);

    // only batch 3 contributes to the output (logits[-1]; no cross-batch mixing)
    copy4_kernel<<<dim3((TT * EE / 4 + 255) / 256), dim3(256), 0, stream>>>(
        (float4*)x, (const float4*)(idx + (size_t)3 * TT * EE), TT * EE / 4);

    for (int l = 0; l < NLAYER; l++) {
        const size_t lw = (size_t)l;
        pack_qkv_kernel<<<dim3(12, 1, 36), dim3(256), 0, stream>>>(
            wq + lw * HNN * EE * HSS, wk + lw * HNN * EE * HSS, wv + lw * HNN * EE * HSS, Wqkv);
        pack_t_kernel<<<dim3(12, 12), dim3(256), 0, stream>>>(wproj + lw * EE * EE, EE, Wproj, EE);
        pack_t_kernel<<<dim3(12, 48), dim3(256), 0, stream>>>(w1 + lw * EE * FFD, FFD, W1t, EE);
        pack_t_kernel<<<dim3(48, 12), dim3(256), 0, stream>>>(w2 + lw * FFD * EE, EE, W2t, FFD);

        ln_kernel<<<dim3(TT), dim3(256), 0, stream>>>(x, ln1g + lw * EE, ln1b + lw * EE, h_bf);
        gemm_bf16<0><<<dim3(288), dim3(256), 0, stream>>>(
            h_bf, Wqkv, bq + lw * EE, bk + lw * EE, bv + lw * EE, nullptr, qkvb,
            QKVN, EE, 16, 1, EE);
        vtrans_kernel<<<dim3(768), dim3(256), 0, stream>>>(qkvb, vTb);
        attn_mfma<<<dim3(1536), dim3(256), 0, stream>>>(qkvb, vTb, o_bf);
        gemm_bf16<1><<<dim3(384), dim3(256), 0, stream>>>(
            o_bf, Wproj, bproj + lw * EE, nullptr, nullptr, x, nullptr,
            EE, EE, 16, 4, 192);
        ln_kernel<<<dim3(TT), dim3(256), 0, stream>>>(x, ln2g + lw * EE, ln2b + lw * EE, h_bf);
        gemm_bf16<2><<<dim3(384), dim3(256), 0, stream>>>(
            h_bf, W1t, b1 + lw * FFD, nullptr, nullptr, nullptr, ffb,
            FFD, EE, 16, 1, EE);
        gemm_bf16<1><<<dim3(384), dim3(256), 0, stream>>>(
            ffb, W2t, b2 + lw * EE, nullptr, nullptr, x, nullptr,
            EE, FFD, 16, 4, 768);
    }

    ln_kernel<<<dim3(TT), dim3(256), 0, stream>>>(x, lnfg, lnfb, h_bf);
    pack_t_kernel<<<dim3(12, 48), dim3(256), 0, stream>>>(fw1, FFD, W1t, EE);
    pack_t_kernel<<<dim3(48, 12), dim3(256), 0, stream>>>(fw2, EE, W2t, FFD);
    gemm_bf16<2><<<dim3(384), dim3(256), 0, stream>>>(
        h_bf, W1t, fb1, nullptr, nullptr, nullptr, ffb, FFD, EE, 16, 1, EE);
    gemm_bf16<3><<<dim3(96), dim3(256), 0, stream>>>(
        ffb, W2t, fb2, nullptr, nullptr, x, nullptr, EE, FFD, 16, 1, FFD);
    head_kernel<<<dim3(TT), dim3(256), 0, stream>>>(x, hw, hb, out);
}

// Round 8
// 1441.696 us; speedup vs baseline: 1.2838x; 1.0409x over previous
//
#include <hip/hip_runtime.h>
#include <math.h>

#define TT 2048
#define EE 768
#define HNN 12
#define HSS 64
#define NLAYER 6
#define FFD 3072
#define QKVN 2304

constexpr float LN_EPS = 1e-5f;
constexpr float ATT_SCALE = 0.03608439182435161f; // 1/sqrt(768) (reference divides by sqrt(n_embed))
// log2-domain scale: exp(x*A) == exp2(x*A*log2e)
constexpr float ATT_SCALE_L2E = 0.03608439182435161f * 1.4426950408889634f;

typedef __attribute__((ext_vector_type(8))) short bf16x8;
typedef __attribute__((ext_vector_type(4))) float f32x4;

__device__ __forceinline__ ushort f2bf(float f) {
    union { float f; uint u; } c; c.f = f;
    const uint u = c.u;
    return (ushort)((u + 0x7fffu + ((u >> 16) & 1u)) >> 16);
}

__device__ __forceinline__ void gload16(const void* g, void* l) {
    __builtin_amdgcn_global_load_lds((const __attribute__((address_space(1))) void*)g,
                                     (__attribute__((address_space(3))) void*)l, 16, 0, 0);
}

// ---------------------------------------------------------------- copy ----
__global__ __launch_bounds__(256) void copy4_kernel(float4* __restrict__ dst,
                                                    const float4* __restrict__ src, int n4) {
    int i = blockIdx.x * 256 + threadIdx.x;
    if (i < n4) dst[i] = src[i];
}

// ----------------------------------------------------------- layernorm ----
__global__ __launch_bounds__(256) void ln_kernel(const float* __restrict__ in,
                                                 const float* __restrict__ g,
                                                 const float* __restrict__ b,
                                                 ushort* __restrict__ out) {
    __shared__ float red[8];
    const int t = blockIdx.x;
    const int tid = threadIdx.x;
    const float* row = in + (size_t)t * EE;
    float v0 = row[tid], v1 = row[tid + 256], v2 = row[tid + 512];
    float s = v0 + v1 + v2;
#pragma unroll
    for (int m = 1; m < 64; m <<= 1) s += __shfl_xor(s, m, 64);
    if ((tid & 63) == 0) red[tid >> 6] = s;
    __syncthreads();
    const float mean = (red[0] + red[1] + red[2] + red[3]) * (1.0f / EE);
    const float d0 = v0 - mean, d1 = v1 - mean, d2 = v2 - mean;
    float qq = d0 * d0 + d1 * d1 + d2 * d2;
#pragma unroll
    for (int m = 1; m < 64; m <<= 1) qq += __shfl_xor(qq, m, 64);
    __syncthreads();
    if ((tid & 63) == 0) red[tid >> 6] = qq;
    __syncthreads();
    const float var = (red[0] + red[1] + red[2] + red[3]) * (1.0f / EE);
    const float rstd = rsqrtf(var + LN_EPS);
    ushort* orow = out + (size_t)t * EE;
    orow[tid]       = f2bf(d0 * rstd * g[tid]       + b[tid]);
    orow[tid + 256] = f2bf(d1 * rstd * g[tid + 256] + b[tid + 256]);
    orow[tid + 512] = f2bf(d2 * rstd * g[tid + 512] + b[tid + 512]);
}

// --------------------------------------------------- weight pack (fp32->bf16^T)
__device__ __forceinline__ void transpose64(const float* __restrict__ src, int sld,
                                            ushort* __restrict__ dst, int dld,
                                            int k0, int n0, int tid) {
    __shared__ float t[64][68];
#pragma unroll
    for (int p = 0; p < 4; p++) {
        const int kr = p * 16 + (tid >> 4);
        *(float4*)&t[kr][(tid & 15) * 4] =
            *(const float4*)&src[(size_t)(k0 + kr) * sld + n0 + (tid & 15) * 4];
    }
    __syncthreads();
#pragma unroll
    for (int q = 0; q < 2; q++) {
        const int nl = q * 32 + (tid >> 3);
        const int kc = (tid & 7) * 8;
        ushort v[8];
#pragma unroll
        for (int j = 0; j < 8; j++) v[j] = f2bf(t[kc + j][nl]);
        uint4 o;
        o.x = (uint)v[0] | ((uint)v[1] << 16);
        o.y = (uint)v[2] | ((uint)v[3] << 16);
        o.z = (uint)v[4] | ((uint)v[5] << 16);
        o.w = (uint)v[6] | ((uint)v[7] << 16);
        *(uint4*)&dst[(size_t)(n0 + nl) * dld + k0 + kc] = o;
    }
}

__global__ __launch_bounds__(256) void pack_t_kernel(const float* __restrict__ src, int sld,
                                                     ushort* __restrict__ dst, int dld) {
    transpose64(src, sld, dst, dld, blockIdx.x * 64, blockIdx.y * 64, threadIdx.x);
}

__global__ __launch_bounds__(256) void pack_qkv_kernel(const float* __restrict__ wq,
                                                       const float* __restrict__ wk,
                                                       const float* __restrict__ wv,
                                                       ushort* __restrict__ dst) {
    const int z = blockIdx.z;
    const int which = z / HNN, hd = z % HNN;
    const float* src = (which == 0 ? wq : which == 1 ? wk : wv) + (size_t)hd * EE * HSS;
    ushort* d = dst + (size_t)(which * EE + hd * HSS) * EE;
    transpose64(src, HSS, d, EE, blockIdx.x * 64, 0, threadIdx.x);
}

// ------------------------------------------------------------ V transpose ----
__global__ __launch_bounds__(256) void vtrans_kernel(const ushort* __restrict__ qkv,
                                                     ushort* __restrict__ vT) {
    const int t = blockIdx.x * 256 + threadIdx.x;  // 0..196607
    const int d = t & 63;
    const int rest = t >> 6;
    const int tb = rest & 255;   // token block of 8
    const int hd = rest >> 8;    // 0..11
    const ushort* src = qkv + 1536 + hd * 64 + d;
    ushort v[8];
#pragma unroll
    for (int j = 0; j < 8; j++) v[j] = src[(size_t)(tb * 8 + j) * QKVN];
    uint4 o;
    o.x = (uint)v[0] | ((uint)v[1] << 16);
    o.y = (uint)v[2] | ((uint)v[3] << 16);
    o.z = (uint)v[4] | ((uint)v[5] << 16);
    o.w = (uint)v[6] | ((uint)v[7] << 16);
    *(uint4*)&vT[((size_t)hd * 64 + d) * TT + tb * 8] = o;
}

// ---------------------------------------------------------- bf16 GEMM ----
// R11: 64x128 tile (was 128x128).  The 128^2 grids were 288-384 blocks =
// 1-1.5 blocks/CU -- the per-iter vmcnt(0)+barrier drain had no co-resident
// waves to hide under (needs >=3 blocks/CU).  64x128 doubles the grid
// (576-768 blocks, 2.3-3/CU), LDS 24KB, ~70 VGPR -> cross-block overlap
// absorbs the drain.  A-traffic doubles but A (3MB bf16) is L2-resident.
// 4 waves: wave w computes rows 0..63, cols w*32..w*32+31 (4x2 MFMA grid).
// XCD-contiguous remap (mb fastest), 2-phase pipeline, split-K via atomicAdd
// (EPI=1), LDS swizzle both-sides as before.
template <int EPI>
__global__ __launch_bounds__(256) void gemm_bf16(const ushort* __restrict__ A,
                                                 const ushort* __restrict__ Bt,
                                                 const float* __restrict__ b0,
                                                 const float* __restrict__ b1,
                                                 const float* __restrict__ b2,
                                                 float* __restrict__ outF,
                                                 ushort* __restrict__ outB,
                                                 int N, int K,
                                                 int nby, int KS, int Kslice) {
    __shared__ ushort Al[2][64 * 32];
    __shared__ ushort Bl[2][128 * 32];
    const int tid = threadIdx.x;
    const int wave = tid >> 6, lane = tid & 63;
    const int l15 = lane & 15, q4 = lane >> 4;

    const int nwg = gridDim.x;
    const int wgid = ((int)blockIdx.x & 7) * (nwg >> 3) + ((int)blockIdx.x >> 3);
    const int mb = wgid % nby;           // nby = M/64 = 32
    const int t2 = wgid / nby;
    const int ks = t2 % KS;
    const int nb = t2 / KS;
    const int m0 = mb * 64, n0 = nb * 128;
    const int kbase = ks * Kslice;

    // staging: lane -> row lane>>2, source colblk swizzled by row
    const int srow = lane >> 2;
    const int scb = (lane & 3) ^ ((lane >> 3) & 3);
    const ushort* Ag  = A + (size_t)(m0 + wave * 16 + srow) * K + kbase + scb * 8;
    const ushort* Bg0 = Bt + (size_t)(n0 + wave * 32 + srow) * K + kbase + scb * 8;
    const ushort* Bg1 = Bg0 + (size_t)16 * K;

    auto stage = [&](int buf, int kk) {
        const int off = kk * 32;
        gload16(Ag + off, &Al[buf][(wave * 16) * 32]);
        gload16(Bg0 + off, &Bl[buf][(wave * 32) * 32]);
        gload16(Bg1 + off, &Bl[buf][(wave * 32 + 16) * 32]);
    };

    f32x4 acc[4][2];
#pragma unroll
    for (int i = 0; i < 4; i++)
#pragma unroll
        for (int j = 0; j < 2; j++) acc[i][j] = (f32x4){0.f, 0.f, 0.f, 0.f};

    stage(0, 0);
    __syncthreads();

    const int niter = Kslice >> 5;
    const int cq = (q4 ^ ((l15 >> 1) & 3)) * 8;  // swizzled read col (ushorts)

    for (int i = 0; i < niter; i++) {
        const int buf = i & 1;
        if (i + 1 < niter) stage(buf ^ 1, i + 1);
        bf16x8 af[4], bfr[2];
#pragma unroll
        for (int ii = 0; ii < 4; ii++)
            af[ii] = *(const bf16x8*)&Al[buf][(ii * 16 + l15) * 32 + cq];
#pragma unroll
        for (int j = 0; j < 2; j++)
            bfr[j] = *(const bf16x8*)&Bl[buf][(wave * 32 + j * 16 + l15) * 32 + cq];
#pragma unroll
        for (int ii = 0; ii < 4; ii++)
#pragma unroll
            for (int j = 0; j < 2; j++)
                acc[ii][j] = __builtin_amdgcn_mfma_f32_16x16x32_bf16(af[ii], bfr[j], acc[ii][j], 0, 0, 0);
        __syncthreads();
    }

#pragma unroll
    for (int i = 0; i < 4; i++) {
        const int row = m0 + i * 16 + q4 * 4;
#pragma unroll
        for (int j = 0; j < 2; j++) {
            const int col = n0 + wave * 32 + j * 16 + l15;
            float bias;
            if constexpr (EPI == 0)
                bias = (col < 768) ? b0[col] : (col < 1536 ? b1[col - 768] : b2[col - 1536]);
            else
                bias = (EPI == 1 && ks != 0) ? 0.f : b0[col];
#pragma unroll
            for (int r = 0; r < 4; r++) {
                const float v = acc[i][j][r] + bias;
                const size_t idx = (size_t)(row + r) * N + col;
                if constexpr (EPI == 0) {
                    outB[idx] = f2bf(v);
                } else if constexpr (EPI == 1) {
                    atomicAdd(&outF[idx], v);
                } else if constexpr (EPI == 2) {
                    outB[idx] = f2bf(0.5f * v * (1.0f + erff(v * 0.70710678118654752f)));
                } else {
                    outF[idx] = v;
                }
            }
        }
    }
}

// ----------------------------------------------------- MFMA attention ----
// (unchanged from R7/R10: in-block key-split, LDS combine, (256,2) bounds)
__global__ __launch_bounds__(256, 2) void attn_mfma(const ushort* __restrict__ qkv,
                                                    const ushort* __restrict__ vT,
                                                    ushort* __restrict__ o_bf) {
    __shared__ __align__(16) uint  Ps[4][16 * 36];
    __shared__ __align__(16) float Po[4][16 * 64];
    __shared__ float Pm[4][16];
    __shared__ float Pl[4][16];

    const int tid = threadIdx.x;
    const int wave = tid >> 6, lane = tid & 63;
    const int l15 = lane & 15, q4 = lane >> 4;

    // block decode: XCD x owns head x (+ half of head 8+(x>>1)); qi descending
    const int x = (int)blockIdx.x & 7, r = (int)blockIdx.x >> 3;
    int head, qi;
    if (r < 128) { head = x;            qi = 127 - r; }
    else         { head = 8 + (x >> 1); qi = 2 * (191 - r) + (x & 1); }
    const int nkt = (qi >> 2) + 1;       // k-tiles for this q-tile (1..32)
    const int per = (nkt + 3) >> 2;      // k-tiles per wave (1..8)
    const int kt0 = wave * per;
    const int kt1 = min(kt0 + per, nkt);
    const int qrow_g = qi * 16 + l15;

    // Q fragments (B-operand of swapped QK^T)
    const ushort* qp = qkv + (size_t)qrow_g * QKVN + head * 64;
    const bf16x8 qa0 = *(const bf16x8*)&qp[q4 * 8];
    const bf16x8 qa1 = *(const bf16x8*)&qp[32 + q4 * 8];

    // per-lane K / V^T bases
    const ushort* kbase = qkv + 768 + head * 64 + (size_t)l15 * QKVN + q4 * 8;
    const ushort* vbase = vT + ((size_t)head * 64 + l15) * TT + q4 * 8;

    float m_i = -1e30f, l_i = 0.f;
    f32x4 oacc[4];
#pragma unroll
    for (int n = 0; n < 4; n++) oacc[n] = (f32x4){0.f, 0.f, 0.f, 0.f};

    uint* psrow = &Ps[wave][l15 * 36];

    if (kt0 < kt1) {
        bf16x8 kA[8], kB[8], vC[8];
        // prologue: K tile kt0
        {
            const ushort* kp = kbase + (size_t)kt0 * 64 * QKVN;
#pragma unroll
            for (int n = 0; n < 4; n++)
#pragma unroll
                for (int kb = 0; kb < 2; kb++)
                    kA[n * 2 + kb] = *(const bf16x8*)(kp + (size_t)(n * 16) * QKVN + kb * 32);
        }

        auto body = [&](bf16x8* kc, bf16x8* kn, int kt) {
            // V^T for current tile (latency covered by QK^T + softmax)
            const ushort* vp = vbase + kt * 64;
#pragma unroll
            for (int n = 0; n < 4; n++)
#pragma unroll
                for (int kb = 0; kb < 2; kb++)
                    vC[n * 2 + kb] = *(const bf16x8*)(vp + (size_t)(n * 16) * TT + kb * 32);
            // prefetch K for next tile
            if (kt + 1 < kt1) {
                const ushort* kp = kbase + (size_t)(kt + 1) * 64 * QKVN;
#pragma unroll
                for (int n = 0; n < 4; n++)
#pragma unroll
                    for (int kb = 0; kb < 2; kb++)
                        kn[n * 2 + kb] = *(const bf16x8*)(kp + (size_t)(n * 16) * QKVN + kb * 32);
            }
            // S^T = K Q^T : lane -> q-row l15, keys n*16 + q4*4 + rr
            f32x4 s[4];
#pragma unroll
            for (int n = 0; n < 4; n++) {
                f32x4 a = (f32x4){0.f, 0.f, 0.f, 0.f};
                a = __builtin_amdgcn_mfma_f32_16x16x32_bf16(kc[n * 2], qa0, a, 0, 0, 0);
                a = __builtin_amdgcn_mfma_f32_16x16x32_bf16(kc[n * 2 + 1], qa1, a, 0, 0, 0);
                s[n] = a;
            }
            // scale into log2 domain + causal mask (global last tile only)
            float pe[16];
            const bool diag = (kt == nkt - 1);
#pragma unroll
            for (int n = 0; n < 4; n++) {
                const int k0 = kt * 64 + n * 16 + q4 * 4;
#pragma unroll
                for (int rr = 0; rr < 4; rr++) {
                    float xv = s[n][rr] * ATT_SCALE_L2E;
                    if (diag && (k0 + rr) > qrow_g) xv = -1e30f;
                    pe[n * 4 + rr] = xv;
                }
            }
            // row max: pairwise tree + 2 shfl
            float t8[8];
#pragma unroll
            for (int i = 0; i < 8; i++) t8[i] = fmaxf(pe[i], pe[i + 8]);
            float mx = fmaxf(fmaxf(fmaxf(t8[0], t8[4]), fmaxf(t8[1], t8[5])),
                             fmaxf(fmaxf(t8[2], t8[6]), fmaxf(t8[3], t8[7])));
            mx = fmaxf(mx, __shfl_xor(mx, 16, 64));
            mx = fmaxf(mx, __shfl_xor(mx, 32, 64));
            const float nm = fmaxf(m_i, mx);
            const float al = exp2f(m_i - nm);
#pragma unroll
            for (int i = 0; i < 16; i++) pe[i] = exp2f(pe[i] - nm);
            float s8[8];
#pragma unroll
            for (int i = 0; i < 8; i++) s8[i] = pe[i] + pe[i + 8];
            float rs = ((s8[0] + s8[4]) + (s8[1] + s8[5])) + ((s8[2] + s8[6]) + (s8[3] + s8[7]));
            rs += __shfl_xor(rs, 16, 64);
            rs += __shfl_xor(rs, 32, 64);
            l_i = l_i * al + rs;
            m_i = nm;
            // alpha for O-rows q4*4+rr
            float alr[4];
#pragma unroll
            for (int rr = 0; rr < 4; rr++) alr[rr] = __shfl(al, q4 * 4 + rr, 64);
#pragma unroll
            for (int n = 0; n < 4; n++) {
                oacc[n][0] *= alr[0];
                oacc[n][1] *= alr[1];
                oacc[n][2] *= alr[2];
                oacc[n][3] *= alr[3];
            }
            // P -> A-fragments via per-wave LDS, rotation-swizzled
#pragma unroll
            for (int n = 0; n < 4; n++) {
                uint2 d2;
                d2.x = (uint)f2bf(pe[n * 4 + 0]) | ((uint)f2bf(pe[n * 4 + 1]) << 16);
                d2.y = (uint)f2bf(pe[n * 4 + 2]) | ((uint)f2bf(pe[n * 4 + 3]) << 16);
                *(uint2*)&psrow[(8 * n + 2 * q4 + 4 * l15) & 31] = d2;
            }
            const bf16x8 pa0 = *(const bf16x8*)&psrow[(4 * q4 + 4 * l15) & 31];
            const bf16x8 pa1 = *(const bf16x8*)&psrow[(16 + 4 * q4 + 4 * l15) & 31];
            // O += P V
#pragma unroll
            for (int n = 0; n < 4; n++) {
                oacc[n] = __builtin_amdgcn_mfma_f32_16x16x32_bf16(pa0, vC[n * 2], oacc[n], 0, 0, 0);
                oacc[n] = __builtin_amdgcn_mfma_f32_16x16x32_bf16(pa1, vC[n * 2 + 1], oacc[n], 0, 0, 0);
            }
        };

        int kt = kt0;
        for (;;) {
            body(kA, kB, kt);
            if (++kt >= kt1) break;
            body(kB, kA, kt);
            if (++kt >= kt1) break;
        }
    }

    // partials -> LDS
#pragma unroll
    for (int n = 0; n < 4; n++)
#pragma unroll
        for (int rr = 0; rr < 4; rr++)
            Po[wave][(q4 * 4 + rr) * 64 + n * 16 + l15] = oacc[n][rr];
    if (q4 == 0) {
        Pm[wave][l15] = m_i;
        Pl[wave][l15] = l_i;
    }
    __syncthreads();

    // merge: thread -> (row = tid>>4, 4 cols at (tid&15)*4)
    const int row = tid >> 4;
    const int c4 = (tid & 15) * 4;
    const float m0 = Pm[0][row], m1 = Pm[1][row], m2 = Pm[2][row], m3 = Pm[3][row];
    const float M = fmaxf(fmaxf(m0, m1), fmaxf(m2, m3));
    const float w0 = exp2f(m0 - M), w1 = exp2f(m1 - M), w2 = exp2f(m2 - M), w3 = exp2f(m3 - M);
    const float L = w0 * Pl[0][row] + w1 * Pl[1][row] + w2 * Pl[2][row] + w3 * Pl[3][row];
    const f32x4 o0 = *(const f32x4*)&Po[0][row * 64 + c4];
    const f32x4 o1 = *(const f32x4*)&Po[1][row * 64 + c4];
    const f32x4 o2 = *(const f32x4*)&Po[2][row * 64 + c4];
    const f32x4 o3 = *(const f32x4*)&Po[3][row * 64 + c4];
    const float rl = 1.0f / L;
    uint2 ow;
    {
        const float v0 = (w0 * o0[0] + w1 * o1[0] + w2 * o2[0] + w3 * o3[0]) * rl;
        const float v1 = (w0 * o0[1] + w1 * o1[1] + w2 * o2[1] + w3 * o3[1]) * rl;
        const float v2 = (w0 * o0[2] + w1 * o1[2] + w2 * o2[2] + w3 * o3[2]) * rl;
        const float v3 = (w0 * o0[3] + w1 * o1[3] + w2 * o2[3] + w3 * o3[3]) * rl;
        ow.x = (uint)f2bf(v0) | ((uint)f2bf(v1) << 16);
        ow.y = (uint)f2bf(v2) | ((uint)f2bf(v3) << 16);
    }
    *(uint2*)&o_bf[(size_t)(qi * 16 + row) * EE + head * 64 + c4] = ow;
}

// ---------------------------------------------------------------- head ----
__global__ __launch_bounds__(256) void head_kernel(const float* __restrict__ x,
                                                   const float* __restrict__ hw,
                                                   const float* __restrict__ hb,
                                                   float* __restrict__ out) {
    __shared__ float red[8];
    const int t = blockIdx.x, tid = threadIdx.x;
    const float* row = x + (size_t)t * EE;
    float s = row[tid] * hw[tid] + row[tid + 256] * hw[tid + 256] + row[tid + 512] * hw[tid + 512];
#pragma unroll
    for (int m = 1; m < 64; m <<= 1) s += __shfl_xor(s, m, 64);
    if ((tid & 63) == 0) red[tid >> 6] = s;
    __syncthreads();
    if (tid == 0) out[t] = red[0] + red[1] + red[2] + red[3] + hb[0];
}

// -------------------------------------------------------------- launch ----
extern "C" void kernel_launch(void* const* d_in, const int* in_sizes, int n_in,
                              void* d_out, int out_size, void* d_ws, size_t ws_size,
                              hipStream_t stream) {
    const float* idx   = (const float*)d_in[0];
    const float* wq    = (const float*)d_in[2];
    const float* bq    = (const float*)d_in[3];
    const float* wk    = (const float*)d_in[4];
    const float* bk    = (const float*)d_in[5];
    const float* wv    = (const float*)d_in[6];
    const float* bv    = (const float*)d_in[7];
    const float* wproj = (const float*)d_in[8];
    const float* bproj = (const float*)d_in[9];
    const float* ln1g  = (const float*)d_in[10];
    const float* ln1b  = (const float*)d_in[11];
    const float* ln2g  = (const float*)d_in[12];
    const float* ln2b  = (const float*)d_in[13];
    const float* w1    = (const float*)d_in[14];
    const float* b1    = (const float*)d_in[15];
    const float* w2    = (const float*)d_in[16];
    const float* b2    = (const float*)d_in[17];
    const float* lnfg  = (const float*)d_in[18];
    const float* lnfb  = (const float*)d_in[19];
    const float* fw1   = (const float*)d_in[20];
    const float* fb1   = (const float*)d_in[21];
    const float* fw2   = (const float*)d_in[22];
    const float* fb2   = (const float*)d_in[23];
    const float* hw    = (const float*)d_in[24];
    const float* hb    = (const float*)d_in[25];
    float* out = (float*)d_out;

    // ---- workspace carve (~50 MB) ----
    char* p = (char*)d_ws;
    auto alloc = [&](size_t bytes) { void* r = (void*)p; p += (bytes + 255) & ~(size_t)255; return r; };
    float*  x     = (float*)alloc((size_t)TT * EE * 4);
    ushort* h_bf  = (ushort*)alloc((size_t)TT * EE * 2);
    ushort* qkvb  = (ushort*)alloc((size_t)TT * QKVN * 2);
    ushort* o_bf  = (ushort*)alloc((size_t)TT * EE * 2);
    ushort* ffb   = (ushort*)alloc((size_t)TT * FFD * 2);
    ushort* Wqkv  = (ushort*)alloc((size_t)QKVN * EE * 2);
    ushort* Wproj = (ushort*)alloc((size_t)EE * EE * 2);
    ushort* W1t   = (ushort*)alloc((size_t)FFD * EE * 2);
    ushort* W2t   = (ushort*)alloc((size_t)EE * FFD * 2);
    ushort* vTb   = (ushort*)alloc((size_t)HNN * HSS * TT * 2);

    // only batch 3 contributes to the output (logits[-1]; no cross-batch mixing)
    copy4_kernel<<<dim3((TT * EE / 4 + 255) / 256), dim3(256), 0, stream>>>(
        (float4*)x, (const float4*)(idx + (size_t)3 * TT * EE), TT * EE / 4);

    for (int l = 0; l < NLAYER; l++) {
        const size_t lw = (size_t)l;
        pack_qkv_kernel<<<dim3(12, 1, 36), dim3(256), 0, stream>>>(
            wq + lw * HNN * EE * HSS, wk + lw * HNN * EE * HSS, wv + lw * HNN * EE * HSS, Wqkv);
        pack_t_kernel<<<dim3(12, 12), dim3(256), 0, stream>>>(wproj + lw * EE * EE, EE, Wproj, EE);
        pack_t_kernel<<<dim3(12, 48), dim3(256), 0, stream>>>(w1 + lw * EE * FFD, FFD, W1t, EE);
        pack_t_kernel<<<dim3(48, 12), dim3(256), 0, stream>>>(w2 + lw * FFD * EE, EE, W2t, FFD);

        ln_kernel<<<dim3(TT), dim3(256), 0, stream>>>(x, ln1g + lw * EE, ln1b + lw * EE, h_bf);
        // QKV: 32 x 18 = 576 blocks
        gemm_bf16<0><<<dim3(576), dim3(256), 0, stream>>>(
            h_bf, Wqkv, bq + lw * EE, bk + lw * EE, bv + lw * EE, nullptr, qkvb,
            QKVN, EE, 32, 1, EE);
        vtrans_kernel<<<dim3(768), dim3(256), 0, stream>>>(qkvb, vTb);
        attn_mfma<<<dim3(1536), dim3(256), 0, stream>>>(qkvb, vTb, o_bf);
        // proj: 32 x 6, split-K x4 (Kslice 192) -> 768 blocks
        gemm_bf16<1><<<dim3(768), dim3(256), 0, stream>>>(
            o_bf, Wproj, bproj + lw * EE, nullptr, nullptr, x, nullptr,
            EE, EE, 32, 4, 192);
        ln_kernel<<<dim3(TT), dim3(256), 0, stream>>>(x, ln2g + lw * EE, ln2b + lw * EE, h_bf);
        // FF1: 32 x 24 = 768 blocks
        gemm_bf16<2><<<dim3(768), dim3(256), 0, stream>>>(
            h_bf, W1t, b1 + lw * FFD, nullptr, nullptr, nullptr, ffb,
            FFD, EE, 32, 1, EE);
        // FF2: 32 x 6, split-K x4 (Kslice 768) -> 768 blocks
        gemm_bf16<1><<<dim3(768), dim3(256), 0, stream>>>(
            ffb, W2t, b2 + lw * EE, nullptr, nullptr, x, nullptr,
            EE, FFD, 32, 4, 768);
    }

    ln_kernel<<<dim3(TT), dim3(256), 0, stream>>>(x, lnfg, lnfb, h_bf);
    pack_t_kernel<<<dim3(12, 48), dim3(256), 0, stream>>>(fw1, FFD, W1t, EE);
    pack_t_kernel<<<dim3(48, 12), dim3(256), 0, stream>>>(fw2, EE, W2t, FFD);
    gemm_bf16<2><<<dim3(768), dim3(256), 0, stream>>>(
        h_bf, W1t, fb1, nullptr, nullptr, nullptr, ffb, FFD, EE, 32, 1, EE);
    gemm_bf16<3><<<dim3(192), dim3(256), 0, stream>>>(
        ffb, W2t, fb2, nullptr, nullptr, x, nullptr, EE, FFD, 32, 1, FFD);
    head_kernel<<<dim3(TT), dim3(256), 0, stream>>>(x, hw, hb, out);
}